// Round 1
// 1017.815 us; speedup vs baseline: 1.0020x; 1.0020x over previous
//
#include <hip/hip_runtime.h>
#include <hip/hip_bf16.h>
#include <stdint.h>

// MoE FFN: sigmoid router (group-limited greedy top-8 of 64), SwiGLU experts
// (1024->512->1024) + shared expert (1024->2048->1024). All inputs fp32.
// R3: router rebuilt as fp32 tiled scores-GEMM + wave-parallel top-k.
// R4 (this round): GEMM K-loop double-buffered (T3-min recipe) — stage tile
// t+1 into the other LDS buffer BEFORE computing tile t, so the vmcnt(0)
// drain at the barrier overlaps ~400cy of MFMA+ds_read instead of exposing
// full HBM latency (kernel was latency-bound: MfmaUtil 15%, Occ 12%, HBM 15%).
// Routed grids y: 32 -> 4 with persistent m-loop (drops 7168 empty blocks).

#define S_TOK 4096
#define C_DIM 1024
#define E_NUM 64
#define H_DIM 512
#define HS_DIM 2048
#define ROWS_TOTAL (S_TOK * 8)

typedef __attribute__((ext_vector_type(8))) short short8;
typedef __attribute__((ext_vector_type(4))) float f32x4;

static __device__ __forceinline__ unsigned short f2bf(float f) {
    union { float f; uint32_t u; } v; v.f = f;
    uint32_t u = v.u;
    u += 0x7fffu + ((u >> 16) & 1u);   // RNE
    return (unsigned short)(u >> 16);
}

static __device__ __forceinline__ void gl2lds16(const void* g, void* l) {
    __builtin_amdgcn_global_load_lds(
        (const __attribute__((address_space(1))) uint32_t*)g,
        (__attribute__((address_space(3))) uint32_t*)l, 16, 0, 0);
}

// ---------------- router part 1: scores = sigmoid(x @ rw^T), fp32 ----------------
// 32-token x 64-expert tile per block, BK=32, 2x4 register tile per thread.
__global__ __launch_bounds__(256)
void router_scores_k(const float* __restrict__ x, const float* __restrict__ rw,
                     float* __restrict__ scores) {
    int t0 = blockIdx.x * 32;
    __shared__ float xs[32][36];    // pad 36: float4-aligned rows
    __shared__ float wsm[64][36];
    int t = threadIdx.x;
    int tx = t & 15, ty = t >> 4;   // tx: 4-expert group, ty: 2-token group
    float acc[2][4] = {};
    for (int k0 = 0; k0 < C_DIM; k0 += 32) {
        {
            int r = t >> 3, c = t & 7;
            *(float4*)&xs[r][c * 4] = *(const float4*)(x + (size_t)(t0 + r) * C_DIM + k0 + c * 4);
        }
        #pragma unroll
        for (int i = 0; i < 2; i++) {
            int idx = t + 256 * i;
            int r = idx >> 3, c = idx & 7;
            *(float4*)&wsm[r][c * 4] = *(const float4*)(rw + (size_t)r * C_DIM + k0 + c * 4);
        }
        __syncthreads();
        #pragma unroll
        for (int kk = 0; kk < 32; kk += 4) {
            float4 a0 = *(const float4*)&xs[ty * 2 + 0][kk];
            float4 a1 = *(const float4*)&xs[ty * 2 + 1][kk];
            #pragma unroll
            for (int j = 0; j < 4; j++) {
                float4 b = *(const float4*)&wsm[tx * 4 + j][kk];
                acc[0][j] += a0.x * b.x + a0.y * b.y + a0.z * b.z + a0.w * b.w;
                acc[1][j] += a1.x * b.x + a1.y * b.y + a1.z * b.z + a1.w * b.w;
            }
        }
        __syncthreads();
    }
    #pragma unroll
    for (int i = 0; i < 2; i++)
        #pragma unroll
        for (int j = 0; j < 4; j++)
            scores[(size_t)(t0 + ty * 2 + i) * E_NUM + tx * 4 + j] =
                1.f / (1.f + __expf(-acc[i][j]));
}

// ---------------- router part 2: wave-parallel grouped top-k ----------------
// one wave per token (4 waves/block). lane = expert.
__global__ __launch_bounds__(256)
void topk_k(const float* __restrict__ scores, const float* __restrict__ ebias,
            int* __restrict__ topk_idx, float* __restrict__ topk_w,
            int* __restrict__ counts) {
    int t = blockIdx.x * 4 + (threadIdx.x >> 6);
    int e = threadIdx.x & 63;
    float sc = scores[(size_t)t * E_NUM + e];
    float sb = sc + ebias[e];
    // group-of-8 top-2 via xor-shuffle merges (exact max/min, no arithmetic)
    float m1 = sb, m2 = -1e30f;
    #pragma unroll
    for (int off = 1; off <= 4; off <<= 1) {
        float o1 = __shfl_xor(m1, off);
        float o2 = __shfl_xor(m2, off);
        float hi = fmaxf(m1, o1), lo = fminf(m1, o1);
        m2 = fmaxf(lo, fmaxf(m2, o2));
        m1 = hi;
    }
    float grp = m1 + m2;   // same add order as ref (top1 + top2)
    float grpv[8];
    #pragma unroll
    for (int g = 0; g < 8; g++) grpv[g] = __shfl(grp, g * 8);
    // top-4 groups, strict > ascending scan -> lowest index on ties (lax.top_k)
    unsigned gsel = 0;
    #pragma unroll
    for (int k = 0; k < 4; k++) {
        float best = -1e30f; int bi = 0;
        #pragma unroll
        for (int g = 0; g < 8; g++)
            if (!((gsel >> g) & 1) && grpv[g] > best) { best = grpv[g]; bi = g; }
        gsel |= 1u << bi;
    }
    // top-8 experts among selected groups: 8x wave argmax w/ lowest-index ties
    float val = ((gsel >> (e >> 3)) & 1) ? sb : -1e30f;
    int idx[8]; float sv[8]; float wsum = 0.f;
    #pragma unroll
    for (int k = 0; k < 8; k++) {
        uint32_t u = __float_as_uint(val);
        uint32_t mu = (u & 0x80000000u) ? ~u : (u | 0x80000000u);  // monotone map
        unsigned long long key = ((unsigned long long)mu << 6) | (unsigned long long)(63 - e);
        #pragma unroll
        for (int off = 32; off; off >>= 1) {
            unsigned long long ok = __shfl_xor(key, off);
            if (ok > key) key = ok;
        }
        int win = 63 - (int)(key & 63ull);
        idx[k] = win;
        sv[k] = __shfl(sc, win);
        wsum += sv[k];
        if (e == win) val = -1e30f;
    }
    float inv = 1.f / (wsum + 1e-20f);
    if (e < 8) {
        topk_idx[t * 8 + e] = idx[e];
        topk_w[t * 8 + e] = sv[e] * inv;
        atomicAdd(&counts[idx[e]], 1);
    }
}

__global__ void zero_counts_k(int* counts) { counts[threadIdx.x] = 0; }

__global__ void scan_k(const int* __restrict__ counts, int* __restrict__ base,
                       int* __restrict__ cursor) {
    if (threadIdx.x == 0) {
        int s = 0;
        for (int e = 0; e < E_NUM; e++) { base[e] = s; cursor[e] = s; s += counts[e]; }
    }
}

__global__ void scatter_k(const int* __restrict__ topk_idx, const float* __restrict__ topk_w,
                          int* __restrict__ cursor, int* __restrict__ row_token,
                          float* __restrict__ row_wgt) {
    int i = blockIdx.x * blockDim.x + threadIdx.x;
    int e = topk_idx[i];
    int pos = atomicAdd(&cursor[e], 1);
    row_token[pos] = i >> 3;
    row_wgt[pos] = topk_w[i];
}

// ---------------- prepass: fp32 -> bf16 elementwise (x) ----------------
__global__ void cvt_bf16_k(const float* __restrict__ in, unsigned short* __restrict__ out, int n8) {
    int i = blockIdx.x * blockDim.x + threadIdx.x;
    if (i >= n8) return;
    float4 v0 = ((const float4*)in)[2 * i];
    float4 v1 = ((const float4*)in)[2 * i + 1];
    unsigned short t[8] = { f2bf(v0.x), f2bf(v0.y), f2bf(v0.z), f2bf(v0.w),
                            f2bf(v1.x), f2bf(v1.y), f2bf(v1.z), f2bf(v1.w) };
    ((uint4*)out)[i] = *(uint4*)t;
}

// ---------------- prepass: fp32 [R][C] -> bf16 [C][R], batched over z ----------------
#define TP 69
__global__ __launch_bounds__(256)
void transpose_k(const float* __restrict__ in, unsigned short* __restrict__ out, int R, int C) {
    size_t bofs = (size_t)blockIdx.z * R * C;
    in += bofs; out += bofs;
    int r0 = blockIdx.y * 64, c0 = blockIdx.x * 64;
    __shared__ float T[64 * TP];
    int t = threadIdx.x;
    int cg = t & 15, rg = t >> 4;
    #pragma unroll
    for (int ii = 0; ii < 4; ii++) {
        float4 v = *(const float4*)(in + (size_t)(r0 + rg * 4 + ii) * C + c0 + cg * 4);
        T[(cg * 4 + 0) * TP + rg * 4 + ii] = v.x;
        T[(cg * 4 + 1) * TP + rg * 4 + ii] = v.y;
        T[(cg * 4 + 2) * TP + rg * 4 + ii] = v.z;
        T[(cg * 4 + 3) * TP + rg * 4 + ii] = v.w;
    }
    __syncthreads();
    int n = t >> 2, ks = (t & 3) * 16;
    unsigned short h[16];
    #pragma unroll
    for (int u = 0; u < 16; u++) h[u] = f2bf(T[n * TP + ks + u]);
    unsigned short* op = out + (size_t)(c0 + n) * R + r0 + ks;
    *(uint4*)op = *(uint4*)&h[0];
    *(uint4*)(op + 8) = *(uint4*)&h[8];
}

// ---------------- GEMM: C[M,N] = A[M,K] @ Bt[N,K]^T, bf16 in, fp32 acc ----------------
// Double-buffered LDS: stage tile t+1 before computing tile t; one barrier/iter.
template<bool FUSED, bool GATHER, bool GROUPED, int EPI>
__global__ __launch_bounds__(256, 2)
void gemm2_k(const short* __restrict__ A, const short* __restrict__ B1t,
             const short* __restrict__ B2t, void* __restrict__ Cout,
             int M, int N, int K,
             const int* __restrict__ counts, const int* __restrict__ base,
             const int* __restrict__ row_token, const float* __restrict__ row_wgt) {
    int e = GROUPED ? blockIdx.z : 0;
    int Mrows = GROUPED ? counts[e] : M;
    int n0 = blockIdx.x * 128;
    int rowbase = GROUPED ? base[e] : 0;
    const short* B1 = B1t + (GROUPED ? (size_t)e * N * K : 0) + (size_t)n0 * K;
    const short* B2 = FUSED ? (B2t + (GROUPED ? (size_t)e * N * K : 0) + (size_t)n0 * K) : nullptr;

    __shared__ short As[2 * 4096];                    // 2 x 128x32
    __shared__ short Bs1[2 * 4096];
    __shared__ short Bs2[FUSED ? 2 * 4096 : 16];

    int tid = threadIdx.x;
    int lane = tid & 63, w = tid >> 6;
    int wr = w >> 1, wc = w & 1;
    int quad = lane >> 4, l16 = lane & 15;
    int sr = lane >> 2, sc = lane & 3;

    for (int m0 = blockIdx.y * 128; m0 < Mrows; m0 += gridDim.y * 128) {
        const short* aptr[2];
        const short* b1ptr[2];
        const short* b2ptr[2];
        #pragma unroll
        for (int i = 0; i < 2; i++) {
            int row = w * 32 + i * 16 + sr;
            int mrow = m0 + row;
            int cl = mrow < Mrows ? mrow : (Mrows - 1);
            size_t arow;
            if (GATHER)       arow = (size_t)row_token[rowbase + cl];
            else if (GROUPED) arow = (size_t)(rowbase + cl);
            else              arow = (size_t)mrow;
            aptr[i] = A + arow * K + sc * 8;
            b1ptr[i] = B1 + (size_t)row * K + sc * 8;
            if (FUSED) b2ptr[i] = B2 + (size_t)row * K + sc * 8;
        }

        f32x4 acc1[4][4] = {};
        f32x4 acc2[4][4] = {};

        const int nk = K >> 5;
        // prologue: stage tile 0 into buffer 0
        #pragma unroll
        for (int i = 0; i < 2; i++) {
            int lb = (w * 32 + i * 16) * 32;
            gl2lds16(aptr[i], &As[lb]);   aptr[i] += 32;
            gl2lds16(b1ptr[i], &Bs1[lb]); b1ptr[i] += 32;
            if (FUSED) { gl2lds16(b2ptr[i], &Bs2[lb]); b2ptr[i] += 32; }
        }
        __syncthreads();

        for (int t = 0; t < nk; t++) {
            int bofs = (t & 1) * 4096;
            int nofs = 4096 - bofs;
            if (t + 1 < nk) {                          // prefetch next tile (async)
                #pragma unroll
                for (int i = 0; i < 2; i++) {
                    int lb = nofs + (w * 32 + i * 16) * 32;
                    gl2lds16(aptr[i], &As[lb]);   aptr[i] += 32;
                    gl2lds16(b1ptr[i], &Bs1[lb]); b1ptr[i] += 32;
                    if (FUSED) { gl2lds16(b2ptr[i], &Bs2[lb]); b2ptr[i] += 32; }
                }
            }
            short8 a[4], b1[4], b2[4];
            #pragma unroll
            for (int i = 0; i < 4; i++)
                a[i] = *(const short8*)&As[bofs + (wr * 64 + i * 16 + l16) * 32 + quad * 8];
            #pragma unroll
            for (int j = 0; j < 4; j++) {
                b1[j] = *(const short8*)&Bs1[bofs + (wc * 64 + j * 16 + l16) * 32 + quad * 8];
                if (FUSED)
                    b2[j] = *(const short8*)&Bs2[bofs + (wc * 64 + j * 16 + l16) * 32 + quad * 8];
            }
            #pragma unroll
            for (int i = 0; i < 4; i++)
                #pragma unroll
                for (int j = 0; j < 4; j++) {
                    acc1[i][j] = __builtin_amdgcn_mfma_f32_16x16x32_bf16(a[i], b1[j], acc1[i][j], 0, 0, 0);
                    if (FUSED)
                        acc2[i][j] = __builtin_amdgcn_mfma_f32_16x16x32_bf16(a[i], b2[j], acc2[i][j], 0, 0, 0);
                }
            __syncthreads();   // drains vmcnt: waits on NEXT tile's loads, issued pre-compute
        }

        #pragma unroll
        for (int i = 0; i < 4; i++) {
            #pragma unroll
            for (int rr = 0; rr < 4; rr++) {
                int row = m0 + wr * 64 + i * 16 + quad * 4 + rr;
                if (row >= Mrows) continue;
                size_t orow = GROUPED ? (size_t)(rowbase + row) : (size_t)row;
                int tok = 0; float scl = 0.f;
                if (EPI == 2) { tok = row_token[rowbase + row]; scl = row_wgt[rowbase + row]; }
                #pragma unroll
                for (int j = 0; j < 4; j++) {
                    int n = n0 + wc * 64 + j * 16 + l16;
                    float v = acc1[i][j][rr];
                    if (EPI == 0) {
                        float u = acc2[i][j][rr];
                        float h = v / (1.f + __expf(-v)) * u;
                        ((unsigned short*)Cout)[orow * N + n] = f2bf(h);
                    } else if (EPI == 1) {
                        ((float*)Cout)[orow * N + n] = v;
                    } else {
                        atomicAdd(&((float*)Cout)[(size_t)tok * N + n], v * scl);
                    }
                }
            }
        }
    }
}

// ---------------- launch ----------------
extern "C" void kernel_launch(void* const* d_in, const int* in_sizes, int n_in,
                              void* d_out, int out_size, void* d_ws, size_t ws_size,
                              hipStream_t stream) {
    const float* x        = (const float*)d_in[0];
    const float* router_w = (const float*)d_in[1];
    const float* e_bias   = (const float*)d_in[2];
    const float* gate_w   = (const float*)d_in[3];
    const float* up_w     = (const float*)d_in[4];
    const float* down_w   = (const float*)d_in[5];
    const float* sh_gate  = (const float*)d_in[6];
    const float* sh_up    = (const float*)d_in[7];
    const float* sh_down  = (const float*)d_in[8];
    float* out = (float*)d_out;
    char* ws = (char*)d_ws;

    int*   counts    = (int*)(ws);
    int*   base      = (int*)(ws + 256);
    int*   cursor    = (int*)(ws + 512);
    int*   topk_idx  = (int*)(ws + 1024);
    float* topk_w    = (float*)(ws + 1024 + 131072);
    int*   row_token = (int*)(ws + 1024 + 2 * 131072);
    float* row_wgt   = (float*)(ws + 1024 + 3 * 131072);
    float* scoresbuf = (float*)(ws + 1024 + 4 * 131072);           // 1 MB
    const size_t MB = 1u << 20;
    unsigned short* xb        = (unsigned short*)(ws + 2 * MB);    // 8 MB
    unsigned short* Hs        = (unsigned short*)(ws + 10 * MB);   // 16 MB
    unsigned short* Hr        = (unsigned short*)(ws + 26 * MB);   // 32 MB
    unsigned short* sh_gate_t = (unsigned short*)(ws + 58 * MB);   // 4 MB
    unsigned short* sh_up_t   = (unsigned short*)(ws + 62 * MB);   // 4 MB
    unsigned short* sh_down_t = (unsigned short*)(ws + 66 * MB);   // 4 MB
    unsigned short* gate_t    = (unsigned short*)(ws + 70 * MB);   // 64 MB
    unsigned short* up_t      = (unsigned short*)(ws + 134 * MB);  // 64 MB
    unsigned short* down_t    = (unsigned short*)(ws + 198 * MB);  // 64 MB -> 262 MB

    // ---- routing ----
    zero_counts_k<<<1, 64, 0, stream>>>(counts);
    router_scores_k<<<S_TOK / 32, 256, 0, stream>>>(x, router_w, scoresbuf);
    topk_k<<<S_TOK / 4, 256, 0, stream>>>(scoresbuf, e_bias, topk_idx, topk_w, counts);
    scan_k<<<1, 64, 0, stream>>>(counts, base, cursor);
    scatter_k<<<ROWS_TOTAL / 256, 256, 0, stream>>>(topk_idx, topk_w, cursor, row_token, row_wgt);

    // ---- prepass: bf16 conversion + weight transposes ----
    cvt_bf16_k<<<S_TOK * C_DIM / 8 / 256, 256, 0, stream>>>(x, xb, S_TOK * C_DIM / 8);
    transpose_k<<<dim3(HS_DIM / 64, C_DIM / 64, 1), 256, 0, stream>>>(sh_gate, sh_gate_t, C_DIM, HS_DIM);
    transpose_k<<<dim3(HS_DIM / 64, C_DIM / 64, 1), 256, 0, stream>>>(sh_up,   sh_up_t,   C_DIM, HS_DIM);
    transpose_k<<<dim3(C_DIM / 64, HS_DIM / 64, 1), 256, 0, stream>>>(sh_down, sh_down_t, HS_DIM, C_DIM);
    transpose_k<<<dim3(H_DIM / 64, C_DIM / 64, E_NUM), 256, 0, stream>>>(gate_w, gate_t, C_DIM, H_DIM);
    transpose_k<<<dim3(H_DIM / 64, C_DIM / 64, E_NUM), 256, 0, stream>>>(up_w,   up_t,   C_DIM, H_DIM);
    transpose_k<<<dim3(C_DIM / 64, H_DIM / 64, E_NUM), 256, 0, stream>>>(down_w, down_t, H_DIM, C_DIM);

    // ---- shared expert ----
    gemm2_k<true, false, false, 0><<<dim3(HS_DIM / 128, S_TOK / 128, 1), 256, 0, stream>>>(
        (const short*)xb, (const short*)sh_gate_t, (const short*)sh_up_t, Hs,
        S_TOK, HS_DIM, C_DIM, nullptr, nullptr, nullptr, nullptr);
    gemm2_k<false, false, false, 1><<<dim3(C_DIM / 128, S_TOK / 128, 1), 256, 0, stream>>>(
        (const short*)Hs, (const short*)sh_down_t, nullptr, out,
        S_TOK, C_DIM, HS_DIM, nullptr, nullptr, nullptr, nullptr);

    // ---- routed experts ----
    gemm2_k<true, true, true, 0><<<dim3(H_DIM / 128, 4, E_NUM), 256, 0, stream>>>(
        (const short*)xb, (const short*)gate_t, (const short*)up_t, Hr,
        0, H_DIM, C_DIM, counts, base, row_token, row_wgt);
    gemm2_k<false, false, true, 2><<<dim3(C_DIM / 128, 4, E_NUM), 256, 0, stream>>>(
        (const short*)Hr, (const short*)down_t, nullptr, out,
        0, C_DIM, H_DIM, counts, base, row_token, row_wgt);
}

// Round 2
// 994.609 us; speedup vs baseline: 1.0254x; 1.0233x over previous
//
#include <hip/hip_runtime.h>
#include <hip/hip_bf16.h>
#include <stdint.h>

// MoE FFN: sigmoid router (group-limited greedy top-8 of 64), SwiGLU experts
// (1024->512->1024) + shared expert (1024->2048->1024). All inputs fp32.
// R5: (a) routed-down combine via O-buffer + gather kernel (was 33.5M fp32
// atomicAdds, suspected ~200-300us hidden cost); O overlays dead gate_t/up_t
// region (exactly 128 MiB). (b) GEMM K-loop: 3-slot LDS ring, 2-deep
// prefetch, counted s_waitcnt vmcnt(6|4) + raw s_barrier + sched_barrier(0)
// instead of __syncthreads' vmcnt(0) full drain (T3/T4-min recipe).
// (c) scan_k -> wave shuffle scan.

#define S_TOK 4096
#define C_DIM 1024
#define E_NUM 64
#define H_DIM 512
#define HS_DIM 2048
#define ROWS_TOTAL (S_TOK * 8)

typedef __attribute__((ext_vector_type(8))) short short8;
typedef __attribute__((ext_vector_type(4))) float f32x4;

static __device__ __forceinline__ unsigned short f2bf(float f) {
    union { float f; uint32_t u; } v; v.f = f;
    uint32_t u = v.u;
    u += 0x7fffu + ((u >> 16) & 1u);   // RNE
    return (unsigned short)(u >> 16);
}

static __device__ __forceinline__ void gl2lds16(const void* g, void* l) {
    __builtin_amdgcn_global_load_lds(
        (const __attribute__((address_space(1))) uint32_t*)g,
        (__attribute__((address_space(3))) uint32_t*)l, 16, 0, 0);
}

// ---------------- router part 1: scores = sigmoid(x @ rw^T), fp32 ----------------
__global__ __launch_bounds__(256)
void router_scores_k(const float* __restrict__ x, const float* __restrict__ rw,
                     float* __restrict__ scores) {
    int t0 = blockIdx.x * 32;
    __shared__ float xs[32][36];
    __shared__ float wsm[64][36];
    int t = threadIdx.x;
    int tx = t & 15, ty = t >> 4;
    float acc[2][4] = {};
    for (int k0 = 0; k0 < C_DIM; k0 += 32) {
        {
            int r = t >> 3, c = t & 7;
            *(float4*)&xs[r][c * 4] = *(const float4*)(x + (size_t)(t0 + r) * C_DIM + k0 + c * 4);
        }
        #pragma unroll
        for (int i = 0; i < 2; i++) {
            int idx = t + 256 * i;
            int r = idx >> 3, c = idx & 7;
            *(float4*)&wsm[r][c * 4] = *(const float4*)(rw + (size_t)r * C_DIM + k0 + c * 4);
        }
        __syncthreads();
        #pragma unroll
        for (int kk = 0; kk < 32; kk += 4) {
            float4 a0 = *(const float4*)&xs[ty * 2 + 0][kk];
            float4 a1 = *(const float4*)&xs[ty * 2 + 1][kk];
            #pragma unroll
            for (int j = 0; j < 4; j++) {
                float4 b = *(const float4*)&wsm[tx * 4 + j][kk];
                acc[0][j] += a0.x * b.x + a0.y * b.y + a0.z * b.z + a0.w * b.w;
                acc[1][j] += a1.x * b.x + a1.y * b.y + a1.z * b.z + a1.w * b.w;
            }
        }
        __syncthreads();
    }
    #pragma unroll
    for (int i = 0; i < 2; i++)
        #pragma unroll
        for (int j = 0; j < 4; j++)
            scores[(size_t)(t0 + ty * 2 + i) * E_NUM + tx * 4 + j] =
                1.f / (1.f + __expf(-acc[i][j]));
}

// ---------------- router part 2: wave-parallel grouped top-k ----------------
__global__ __launch_bounds__(256)
void topk_k(const float* __restrict__ scores, const float* __restrict__ ebias,
            int* __restrict__ topk_idx, float* __restrict__ topk_w,
            int* __restrict__ counts) {
    int t = blockIdx.x * 4 + (threadIdx.x >> 6);
    int e = threadIdx.x & 63;
    float sc = scores[(size_t)t * E_NUM + e];
    float sb = sc + ebias[e];
    float m1 = sb, m2 = -1e30f;
    #pragma unroll
    for (int off = 1; off <= 4; off <<= 1) {
        float o1 = __shfl_xor(m1, off);
        float o2 = __shfl_xor(m2, off);
        float hi = fmaxf(m1, o1), lo = fminf(m1, o1);
        m2 = fmaxf(lo, fmaxf(m2, o2));
        m1 = hi;
    }
    float grp = m1 + m2;
    float grpv[8];
    #pragma unroll
    for (int g = 0; g < 8; g++) grpv[g] = __shfl(grp, g * 8);
    unsigned gsel = 0;
    #pragma unroll
    for (int k = 0; k < 4; k++) {
        float best = -1e30f; int bi = 0;
        #pragma unroll
        for (int g = 0; g < 8; g++)
            if (!((gsel >> g) & 1) && grpv[g] > best) { best = grpv[g]; bi = g; }
        gsel |= 1u << bi;
    }
    float val = ((gsel >> (e >> 3)) & 1) ? sb : -1e30f;
    int idx[8]; float sv[8]; float wsum = 0.f;
    #pragma unroll
    for (int k = 0; k < 8; k++) {
        uint32_t u = __float_as_uint(val);
        uint32_t mu = (u & 0x80000000u) ? ~u : (u | 0x80000000u);
        unsigned long long key = ((unsigned long long)mu << 6) | (unsigned long long)(63 - e);
        #pragma unroll
        for (int off = 32; off; off >>= 1) {
            unsigned long long ok = __shfl_xor(key, off);
            if (ok > key) key = ok;
        }
        int win = 63 - (int)(key & 63ull);
        idx[k] = win;
        sv[k] = __shfl(sc, win);
        wsum += sv[k];
        if (e == win) val = -1e30f;
    }
    float inv = 1.f / (wsum + 1e-20f);
    if (e < 8) {
        topk_idx[t * 8 + e] = idx[e];
        topk_w[t * 8 + e] = sv[e] * inv;
        atomicAdd(&counts[idx[e]], 1);
    }
}

__global__ void zero_counts_k(int* counts) { counts[threadIdx.x] = 0; }

// exclusive scan over 64 expert counts, one wave
__global__ void scan_k(const int* __restrict__ counts, int* __restrict__ base,
                       int* __restrict__ cursor) {
    int e = threadIdx.x;
    int c = counts[e];
    int s = c;
    #pragma unroll
    for (int off = 1; off < 64; off <<= 1) {
        int o = __shfl_up(s, off);
        if (e >= off) s += o;
    }
    int ex = s - c;
    base[e] = ex;
    cursor[e] = ex;
}

__global__ void scatter_k(const int* __restrict__ topk_idx, const float* __restrict__ topk_w,
                          int* __restrict__ cursor, int* __restrict__ row_token,
                          float* __restrict__ row_wgt, int* __restrict__ pos_of) {
    int i = blockIdx.x * blockDim.x + threadIdx.x;
    int e = topk_idx[i];
    int pos = atomicAdd(&cursor[e], 1);
    row_token[pos] = i >> 3;
    row_wgt[pos] = topk_w[i];
    pos_of[i] = pos;
}

// ---------------- combine: out[t] += sum_k O[pos_of[t*8+k]] (weights pre-applied) ---
__global__ __launch_bounds__(256)
void combine_k(const float* __restrict__ O, const int* __restrict__ pos_of,
               float* __restrict__ out) {
    int t = blockIdx.x;
    int c = threadIdx.x;                 // 256 float4 lanes = 1024 floats
    float4 s = ((const float4*)(out + (size_t)t * C_DIM))[c];
    int p[8];
    #pragma unroll
    for (int k = 0; k < 8; k++) p[k] = pos_of[t * 8 + k];
    #pragma unroll
    for (int k = 0; k < 8; k++) {
        float4 v = ((const float4*)(O + (size_t)p[k] * C_DIM))[c];
        s.x += v.x; s.y += v.y; s.z += v.z; s.w += v.w;
    }
    ((float4*)(out + (size_t)t * C_DIM))[c] = s;
}

// ---------------- prepass: fp32 -> bf16 elementwise (x) ----------------
__global__ void cvt_bf16_k(const float* __restrict__ in, unsigned short* __restrict__ out, int n8) {
    int i = blockIdx.x * blockDim.x + threadIdx.x;
    if (i >= n8) return;
    float4 v0 = ((const float4*)in)[2 * i];
    float4 v1 = ((const float4*)in)[2 * i + 1];
    unsigned short t[8] = { f2bf(v0.x), f2bf(v0.y), f2bf(v0.z), f2bf(v0.w),
                            f2bf(v1.x), f2bf(v1.y), f2bf(v1.z), f2bf(v1.w) };
    ((uint4*)out)[i] = *(uint4*)t;
}

// ---------------- prepass: fp32 [R][C] -> bf16 [C][R], batched over z ----------------
#define TP 69
__global__ __launch_bounds__(256)
void transpose_k(const float* __restrict__ in, unsigned short* __restrict__ out, int R, int C) {
    size_t bofs = (size_t)blockIdx.z * R * C;
    in += bofs; out += bofs;
    int r0 = blockIdx.y * 64, c0 = blockIdx.x * 64;
    __shared__ float T[64 * TP];
    int t = threadIdx.x;
    int cg = t & 15, rg = t >> 4;
    #pragma unroll
    for (int ii = 0; ii < 4; ii++) {
        float4 v = *(const float4*)(in + (size_t)(r0 + rg * 4 + ii) * C + c0 + cg * 4);
        T[(cg * 4 + 0) * TP + rg * 4 + ii] = v.x;
        T[(cg * 4 + 1) * TP + rg * 4 + ii] = v.y;
        T[(cg * 4 + 2) * TP + rg * 4 + ii] = v.z;
        T[(cg * 4 + 3) * TP + rg * 4 + ii] = v.w;
    }
    __syncthreads();
    int n = t >> 2, ks = (t & 3) * 16;
    unsigned short h[16];
    #pragma unroll
    for (int u = 0; u < 16; u++) h[u] = f2bf(T[n * TP + ks + u]);
    unsigned short* op = out + (size_t)(c0 + n) * R + r0 + ks;
    *(uint4*)op = *(uint4*)&h[0];
    *(uint4*)(op + 8) = *(uint4*)&h[8];
}

// ---------------- GEMM: C[M,N] = A[M,K] @ Bt[N,K]^T, bf16 in, fp32 acc ----------------
// 3-slot LDS ring, 2-deep prefetch, counted vmcnt waits + raw barriers.
// EPI: 0 = SwiGLU(acc1)*acc2 -> bf16 store; 1 = f32 store; 2 = f32 scaled store (O buffer)
template<bool FUSED, bool GATHER, bool GROUPED, int EPI>
__global__ __launch_bounds__(256, 2)
void gemm2_k(const short* __restrict__ A, const short* __restrict__ B1t,
             const short* __restrict__ B2t, void* __restrict__ Cout,
             int M, int N, int K,
             const int* __restrict__ counts, const int* __restrict__ base,
             const int* __restrict__ row_token, const float* __restrict__ row_wgt) {
    int e = GROUPED ? blockIdx.z : 0;
    int Mrows = GROUPED ? counts[e] : M;
    int n0 = blockIdx.x * 128;
    int rowbase = GROUPED ? base[e] : 0;
    const short* B1 = B1t + (GROUPED ? (size_t)e * N * K : 0) + (size_t)n0 * K;
    const short* B2 = FUSED ? (B2t + (GROUPED ? (size_t)e * N * K : 0) + (size_t)n0 * K) : nullptr;

    __shared__ short As[3 * 4096];                    // 3 x 128x32
    __shared__ short Bs1[3 * 4096];
    __shared__ short Bs2[FUSED ? 3 * 4096 : 16];

    int tid = threadIdx.x;
    int lane = tid & 63, w = tid >> 6;
    int wr = w >> 1, wc = w & 1;
    int quad = lane >> 4, l16 = lane & 15;
    int sr = lane >> 2, sc = lane & 3;

    for (int m0 = blockIdx.y * 128; m0 < Mrows; m0 += gridDim.y * 128) {
        const short* aptr[2];
        const short* b1ptr[2];
        const short* b2ptr[2];
        #pragma unroll
        for (int i = 0; i < 2; i++) {
            int row = w * 32 + i * 16 + sr;
            int mrow = m0 + row;
            int cl = mrow < Mrows ? mrow : (Mrows - 1);
            size_t arow;
            if (GATHER)       arow = (size_t)row_token[rowbase + cl];
            else if (GROUPED) arow = (size_t)(rowbase + cl);
            else              arow = (size_t)mrow;
            aptr[i] = A + arow * K + sc * 8;
            b1ptr[i] = B1 + (size_t)row * K + sc * 8;
            if (FUSED) b2ptr[i] = B2 + (size_t)row * K + sc * 8;
        }

        f32x4 acc1[4][4] = {};
        f32x4 acc2[4][4] = {};

        const int nk = K >> 5;
        auto stage = [&](int slot) {
            #pragma unroll
            for (int i = 0; i < 2; i++) {
                int lb = slot * 4096 + (w * 32 + i * 16) * 32;
                gl2lds16(aptr[i], &As[lb]);   aptr[i] += 32;
                gl2lds16(b1ptr[i], &Bs1[lb]); b1ptr[i] += 32;
                if (FUSED) { gl2lds16(b2ptr[i], &Bs2[lb]); b2ptr[i] += 32; }
            }
        };
        stage(0);
        if (nk > 1) stage(1);

        int slot = 0, nslot = 2;
        for (int t = 0; t < nk; t++) {
            // wait for stage t only: leave the 1 in-flight stage (6 or 4 loads) pending
            if (t + 1 < nk) {
                if constexpr (FUSED) asm volatile("s_waitcnt vmcnt(6)" ::: "memory");
                else                 asm volatile("s_waitcnt vmcnt(4)" ::: "memory");
            } else {
                asm volatile("s_waitcnt vmcnt(0)" ::: "memory");
            }
            __builtin_amdgcn_s_barrier();
            __builtin_amdgcn_sched_barrier(0);   // nothing crosses the barrier (rule #18)

            if (t + 2 < nk) stage(nslot);

            int bofs = slot * 4096;
            short8 a[4], b1[4], b2[4];
            #pragma unroll
            for (int i = 0; i < 4; i++)
                a[i] = *(const short8*)&As[bofs + (wr * 64 + i * 16 + l16) * 32 + quad * 8];
            #pragma unroll
            for (int j = 0; j < 4; j++) {
                b1[j] = *(const short8*)&Bs1[bofs + (wc * 64 + j * 16 + l16) * 32 + quad * 8];
                if (FUSED)
                    b2[j] = *(const short8*)&Bs2[bofs + (wc * 64 + j * 16 + l16) * 32 + quad * 8];
            }
            #pragma unroll
            for (int i = 0; i < 4; i++)
                #pragma unroll
                for (int j = 0; j < 4; j++) {
                    acc1[i][j] = __builtin_amdgcn_mfma_f32_16x16x32_bf16(a[i], b1[j], acc1[i][j], 0, 0, 0);
                    if (FUSED)
                        acc2[i][j] = __builtin_amdgcn_mfma_f32_16x16x32_bf16(a[i], b2[j], acc2[i][j], 0, 0, 0);
                }
            slot = (slot == 2) ? 0 : slot + 1;
            nslot = (nslot == 2) ? 0 : nslot + 1;
        }

        #pragma unroll
        for (int i = 0; i < 4; i++) {
            #pragma unroll
            for (int rr = 0; rr < 4; rr++) {
                int row = m0 + wr * 64 + i * 16 + quad * 4 + rr;
                if (row >= Mrows) continue;
                size_t orow = GROUPED ? (size_t)(rowbase + row) : (size_t)row;
                float scl = 0.f;
                if (EPI == 2) scl = row_wgt[rowbase + row];
                #pragma unroll
                for (int j = 0; j < 4; j++) {
                    int n = n0 + wc * 64 + j * 16 + l16;
                    float v = acc1[i][j][rr];
                    if (EPI == 0) {
                        float u = acc2[i][j][rr];
                        float h = v / (1.f + __expf(-v)) * u;
                        ((unsigned short*)Cout)[orow * N + n] = f2bf(h);
                    } else if (EPI == 1) {
                        ((float*)Cout)[orow * N + n] = v;
                    } else {
                        ((float*)Cout)[orow * N + n] = v * scl;
                    }
                }
            }
        }
        __syncthreads();   // drain + protect ring slots before next m-tile prologue
    }
}

// ---------------- launch ----------------
extern "C" void kernel_launch(void* const* d_in, const int* in_sizes, int n_in,
                              void* d_out, int out_size, void* d_ws, size_t ws_size,
                              hipStream_t stream) {
    const float* x        = (const float*)d_in[0];
    const float* router_w = (const float*)d_in[1];
    const float* e_bias   = (const float*)d_in[2];
    const float* gate_w   = (const float*)d_in[3];
    const float* up_w     = (const float*)d_in[4];
    const float* down_w   = (const float*)d_in[5];
    const float* sh_gate  = (const float*)d_in[6];
    const float* sh_up    = (const float*)d_in[7];
    const float* sh_down  = (const float*)d_in[8];
    float* out = (float*)d_out;
    char* ws = (char*)d_ws;

    int*   counts    = (int*)(ws);
    int*   base      = (int*)(ws + 256);
    int*   cursor    = (int*)(ws + 512);
    int*   topk_idx  = (int*)(ws + 1024);
    float* topk_w    = (float*)(ws + 1024 + 131072);
    int*   row_token = (int*)(ws + 1024 + 2 * 131072);
    float* row_wgt   = (float*)(ws + 1024 + 3 * 131072);
    float* scoresbuf = (float*)(ws + 1024 + 4 * 131072);           // 1 MB
    int*   pos_of    = (int*)(ws + 1664 * 1024);                   // 128 KB, ends < 2MB
    const size_t MB = 1u << 20;
    unsigned short* xb        = (unsigned short*)(ws + 2 * MB);    // 8 MB
    unsigned short* Hs        = (unsigned short*)(ws + 10 * MB);   // 16 MB
    unsigned short* Hr        = (unsigned short*)(ws + 26 * MB);   // 32 MB
    unsigned short* sh_gate_t = (unsigned short*)(ws + 58 * MB);   // 4 MB
    unsigned short* sh_up_t   = (unsigned short*)(ws + 62 * MB);   // 4 MB
    unsigned short* sh_down_t = (unsigned short*)(ws + 66 * MB);   // 4 MB
    unsigned short* gate_t    = (unsigned short*)(ws + 70 * MB);   // 64 MB
    unsigned short* up_t      = (unsigned short*)(ws + 134 * MB);  // 64 MB
    unsigned short* down_t    = (unsigned short*)(ws + 198 * MB);  // 64 MB -> 262 MB
    // O overlays gate_t+up_t (dead after routed fused GEMM): 32768x1024 f32 = 128 MiB
    float* O = (float*)(ws + 70 * MB);

    // ---- routing ----
    zero_counts_k<<<1, 64, 0, stream>>>(counts);
    router_scores_k<<<S_TOK / 32, 256, 0, stream>>>(x, router_w, scoresbuf);
    topk_k<<<S_TOK / 4, 256, 0, stream>>>(scoresbuf, e_bias, topk_idx, topk_w, counts);
    scan_k<<<1, 64, 0, stream>>>(counts, base, cursor);
    scatter_k<<<ROWS_TOTAL / 256, 256, 0, stream>>>(topk_idx, topk_w, cursor, row_token, row_wgt, pos_of);

    // ---- prepass: bf16 conversion + weight transposes ----
    cvt_bf16_k<<<S_TOK * C_DIM / 8 / 256, 256, 0, stream>>>(x, xb, S_TOK * C_DIM / 8);
    transpose_k<<<dim3(HS_DIM / 64, C_DIM / 64, 1), 256, 0, stream>>>(sh_gate, sh_gate_t, C_DIM, HS_DIM);
    transpose_k<<<dim3(HS_DIM / 64, C_DIM / 64, 1), 256, 0, stream>>>(sh_up,   sh_up_t,   C_DIM, HS_DIM);
    transpose_k<<<dim3(C_DIM / 64, HS_DIM / 64, 1), 256, 0, stream>>>(sh_down, sh_down_t, HS_DIM, C_DIM);
    transpose_k<<<dim3(H_DIM / 64, C_DIM / 64, E_NUM), 256, 0, stream>>>(gate_w, gate_t, C_DIM, H_DIM);
    transpose_k<<<dim3(H_DIM / 64, C_DIM / 64, E_NUM), 256, 0, stream>>>(up_w,   up_t,   C_DIM, H_DIM);
    transpose_k<<<dim3(C_DIM / 64, H_DIM / 64, E_NUM), 256, 0, stream>>>(down_w, down_t, H_DIM, C_DIM);

    // ---- shared expert ----
    gemm2_k<true, false, false, 0><<<dim3(HS_DIM / 128, S_TOK / 128, 1), 256, 0, stream>>>(
        (const short*)xb, (const short*)sh_gate_t, (const short*)sh_up_t, Hs,
        S_TOK, HS_DIM, C_DIM, nullptr, nullptr, nullptr, nullptr);
    gemm2_k<false, false, false, 1><<<dim3(C_DIM / 128, S_TOK / 128, 1), 256, 0, stream>>>(
        (const short*)Hs, (const short*)sh_down_t, nullptr, out,
        S_TOK, C_DIM, HS_DIM, nullptr, nullptr, nullptr, nullptr);

    // ---- routed experts ----
    gemm2_k<true, true, true, 0><<<dim3(H_DIM / 128, 4, E_NUM), 256, 0, stream>>>(
        (const short*)xb, (const short*)gate_t, (const short*)up_t, Hr,
        0, H_DIM, C_DIM, counts, base, row_token, row_wgt);
    gemm2_k<false, false, true, 2><<<dim3(C_DIM / 128, 4, E_NUM), 256, 0, stream>>>(
        (const short*)Hr, (const short*)down_t, nullptr, O,
        0, C_DIM, H_DIM, counts, base, row_token, row_wgt);

    // ---- combine routed into out (out already holds shared-expert result) ----
    combine_k<<<S_TOK, 256, 0, stream>>>(O, pos_of, out);
}

// Round 3
// 950.059 us; speedup vs baseline: 1.0735x; 1.0469x over previous
//
#include <hip/hip_runtime.h>
#include <hip/hip_bf16.h>
#include <stdint.h>

// MoE FFN: sigmoid router (group-limited greedy top-8 of 64), SwiGLU experts
// (1024->512->1024) + shared expert (1024->2048->1024). All inputs fp32.
// R6: tile WORKLIST for routed GEMMs. counts ~= 512+-22 and 512 = 4*128, so
// ~half the experts need 5 m-tiles; the old y=4 persistent grid made one
// block per such expert run 2 full K-loops serially -> kernel ~2x balanced
// time (Occ 14% vs 25% ceiling). scan_k now emits (expert, m0) pairs
// (<= 320), grid y=320, one tile per block. Ring pipeline (3-slot, counted
// vmcnt, stage-after-barrier) kept from R5.

#define S_TOK 4096
#define C_DIM 1024
#define E_NUM 64
#define H_DIM 512
#define HS_DIM 2048
#define ROWS_TOTAL (S_TOK * 8)
#define T_TILES 320   // ROWS_TOTAL/128 + E_NUM upper bound on routed m-tiles

typedef __attribute__((ext_vector_type(8))) short short8;
typedef __attribute__((ext_vector_type(4))) float f32x4;

static __device__ __forceinline__ unsigned short f2bf(float f) {
    union { float f; uint32_t u; } v; v.f = f;
    uint32_t u = v.u;
    u += 0x7fffu + ((u >> 16) & 1u);   // RNE
    return (unsigned short)(u >> 16);
}

static __device__ __forceinline__ void gl2lds16(const void* g, void* l) {
    __builtin_amdgcn_global_load_lds(
        (const __attribute__((address_space(1))) uint32_t*)g,
        (__attribute__((address_space(3))) uint32_t*)l, 16, 0, 0);
}

// ---------------- router part 1: scores = sigmoid(x @ rw^T), fp32 ----------------
__global__ __launch_bounds__(256)
void router_scores_k(const float* __restrict__ x, const float* __restrict__ rw,
                     float* __restrict__ scores) {
    int t0 = blockIdx.x * 32;
    __shared__ float xs[32][36];
    __shared__ float wsm[64][36];
    int t = threadIdx.x;
    int tx = t & 15, ty = t >> 4;
    float acc[2][4] = {};
    for (int k0 = 0; k0 < C_DIM; k0 += 32) {
        {
            int r = t >> 3, c = t & 7;
            *(float4*)&xs[r][c * 4] = *(const float4*)(x + (size_t)(t0 + r) * C_DIM + k0 + c * 4);
        }
        #pragma unroll
        for (int i = 0; i < 2; i++) {
            int idx = t + 256 * i;
            int r = idx >> 3, c = idx & 7;
            *(float4*)&wsm[r][c * 4] = *(const float4*)(rw + (size_t)r * C_DIM + k0 + c * 4);
        }
        __syncthreads();
        #pragma unroll
        for (int kk = 0; kk < 32; kk += 4) {
            float4 a0 = *(const float4*)&xs[ty * 2 + 0][kk];
            float4 a1 = *(const float4*)&xs[ty * 2 + 1][kk];
            #pragma unroll
            for (int j = 0; j < 4; j++) {
                float4 b = *(const float4*)&wsm[tx * 4 + j][kk];
                acc[0][j] += a0.x * b.x + a0.y * b.y + a0.z * b.z + a0.w * b.w;
                acc[1][j] += a1.x * b.x + a1.y * b.y + a1.z * b.z + a1.w * b.w;
            }
        }
        __syncthreads();
    }
    #pragma unroll
    for (int i = 0; i < 2; i++)
        #pragma unroll
        for (int j = 0; j < 4; j++)
            scores[(size_t)(t0 + ty * 2 + i) * E_NUM + tx * 4 + j] =
                1.f / (1.f + __expf(-acc[i][j]));
}

// ---------------- router part 2: wave-parallel grouped top-k ----------------
__global__ __launch_bounds__(256)
void topk_k(const float* __restrict__ scores, const float* __restrict__ ebias,
            int* __restrict__ topk_idx, float* __restrict__ topk_w,
            int* __restrict__ counts) {
    int t = blockIdx.x * 4 + (threadIdx.x >> 6);
    int e = threadIdx.x & 63;
    float sc = scores[(size_t)t * E_NUM + e];
    float sb = sc + ebias[e];
    float m1 = sb, m2 = -1e30f;
    #pragma unroll
    for (int off = 1; off <= 4; off <<= 1) {
        float o1 = __shfl_xor(m1, off);
        float o2 = __shfl_xor(m2, off);
        float hi = fmaxf(m1, o1), lo = fminf(m1, o1);
        m2 = fmaxf(lo, fmaxf(m2, o2));
        m1 = hi;
    }
    float grp = m1 + m2;
    float grpv[8];
    #pragma unroll
    for (int g = 0; g < 8; g++) grpv[g] = __shfl(grp, g * 8);
    unsigned gsel = 0;
    #pragma unroll
    for (int k = 0; k < 4; k++) {
        float best = -1e30f; int bi = 0;
        #pragma unroll
        for (int g = 0; g < 8; g++)
            if (!((gsel >> g) & 1) && grpv[g] > best) { best = grpv[g]; bi = g; }
        gsel |= 1u << bi;
    }
    float val = ((gsel >> (e >> 3)) & 1) ? sb : -1e30f;
    int idx[8]; float sv[8]; float wsum = 0.f;
    #pragma unroll
    for (int k = 0; k < 8; k++) {
        uint32_t u = __float_as_uint(val);
        uint32_t mu = (u & 0x80000000u) ? ~u : (u | 0x80000000u);
        unsigned long long key = ((unsigned long long)mu << 6) | (unsigned long long)(63 - e);
        #pragma unroll
        for (int off = 32; off; off >>= 1) {
            unsigned long long ok = __shfl_xor(key, off);
            if (ok > key) key = ok;
        }
        int win = 63 - (int)(key & 63ull);
        idx[k] = win;
        sv[k] = __shfl(sc, win);
        wsum += sv[k];
        if (e == win) val = -1e30f;
    }
    float inv = 1.f / (wsum + 1e-20f);
    if (e < 8) {
        topk_idx[t * 8 + e] = idx[e];
        topk_w[t * 8 + e] = sv[e] * inv;
        atomicAdd(&counts[idx[e]], 1);
    }
}

__global__ void zero_counts_k(int* counts) { counts[threadIdx.x] = 0; }

// exclusive scan over 64 expert counts + m-tile worklist build, one wave
__global__ void scan_k(const int* __restrict__ counts, int* __restrict__ base,
                       int* __restrict__ cursor, int* __restrict__ tile_e,
                       int* __restrict__ tile_m0) {
    int e = threadIdx.x;
    int c = counts[e];
    int s = c;
    #pragma unroll
    for (int off = 1; off < 64; off <<= 1) {
        int o = __shfl_up(s, off);
        if (e >= off) s += o;
    }
    int ex = s - c;
    base[e] = ex;
    cursor[e] = ex;
    // worklist: one (e, m0) entry per 128-row tile of expert e
    int nt = (c + 127) >> 7;
    int ts = nt;
    #pragma unroll
    for (int off = 1; off < 64; off <<= 1) {
        int o = __shfl_up(ts, off);
        if (e >= off) ts += o;
    }
    int tb = ts - nt;
    for (int i = 0; i < nt; i++) { tile_e[tb + i] = e; tile_m0[tb + i] = i * 128; }
    int total = __shfl(ts, 63);
    for (int j = total + e; j < T_TILES; j += 64) tile_e[j] = -1;
}

__global__ void scatter_k(const int* __restrict__ topk_idx, const float* __restrict__ topk_w,
                          int* __restrict__ cursor, int* __restrict__ row_token,
                          float* __restrict__ row_wgt, int* __restrict__ pos_of) {
    int i = blockIdx.x * blockDim.x + threadIdx.x;
    int e = topk_idx[i];
    int pos = atomicAdd(&cursor[e], 1);
    row_token[pos] = i >> 3;
    row_wgt[pos] = topk_w[i];
    pos_of[i] = pos;
}

// ---------------- combine: out[t] += sum_k O[pos_of[t*8+k]] (weights pre-applied) ---
__global__ __launch_bounds__(256)
void combine_k(const float* __restrict__ O, const int* __restrict__ pos_of,
               float* __restrict__ out) {
    int t = blockIdx.x;
    int c = threadIdx.x;
    float4 s = ((const float4*)(out + (size_t)t * C_DIM))[c];
    int p[8];
    #pragma unroll
    for (int k = 0; k < 8; k++) p[k] = pos_of[t * 8 + k];
    #pragma unroll
    for (int k = 0; k < 8; k++) {
        float4 v = ((const float4*)(O + (size_t)p[k] * C_DIM))[c];
        s.x += v.x; s.y += v.y; s.z += v.z; s.w += v.w;
    }
    ((float4*)(out + (size_t)t * C_DIM))[c] = s;
}

// ---------------- prepass: fp32 -> bf16 elementwise (x) ----------------
__global__ void cvt_bf16_k(const float* __restrict__ in, unsigned short* __restrict__ out, int n8) {
    int i = blockIdx.x * blockDim.x + threadIdx.x;
    if (i >= n8) return;
    float4 v0 = ((const float4*)in)[2 * i];
    float4 v1 = ((const float4*)in)[2 * i + 1];
    unsigned short t[8] = { f2bf(v0.x), f2bf(v0.y), f2bf(v0.z), f2bf(v0.w),
                            f2bf(v1.x), f2bf(v1.y), f2bf(v1.z), f2bf(v1.w) };
    ((uint4*)out)[i] = *(uint4*)t;
}

// ---------------- prepass: fp32 [R][C] -> bf16 [C][R], batched over z ----------------
#define TP 69
__global__ __launch_bounds__(256)
void transpose_k(const float* __restrict__ in, unsigned short* __restrict__ out, int R, int C) {
    size_t bofs = (size_t)blockIdx.z * R * C;
    in += bofs; out += bofs;
    int r0 = blockIdx.y * 64, c0 = blockIdx.x * 64;
    __shared__ float T[64 * TP];
    int t = threadIdx.x;
    int cg = t & 15, rg = t >> 4;
    #pragma unroll
    for (int ii = 0; ii < 4; ii++) {
        float4 v = *(const float4*)(in + (size_t)(r0 + rg * 4 + ii) * C + c0 + cg * 4);
        T[(cg * 4 + 0) * TP + rg * 4 + ii] = v.x;
        T[(cg * 4 + 1) * TP + rg * 4 + ii] = v.y;
        T[(cg * 4 + 2) * TP + rg * 4 + ii] = v.z;
        T[(cg * 4 + 3) * TP + rg * 4 + ii] = v.w;
    }
    __syncthreads();
    int n = t >> 2, ks = (t & 3) * 16;
    unsigned short h[16];
    #pragma unroll
    for (int u = 0; u < 16; u++) h[u] = f2bf(T[n * TP + ks + u]);
    unsigned short* op = out + (size_t)(c0 + n) * R + r0 + ks;
    *(uint4*)op = *(uint4*)&h[0];
    *(uint4*)(op + 8) = *(uint4*)&h[8];
}

// ---------------- GEMM: C[M,N] = A[M,K] @ Bt[N,K]^T, bf16 in, fp32 acc ----------------
// 3-slot LDS ring, 2-deep prefetch, counted vmcnt waits + raw barriers.
// WL: one worklist tile per block (balanced routed path).
// EPI: 0 = SwiGLU(acc1)*acc2 -> bf16; 1 = f32 store; 2 = f32 scaled store
template<bool FUSED, bool GATHER, bool WL, int EPI>
__global__ __launch_bounds__(256, 2)
void gemm2_k(const short* __restrict__ A, const short* __restrict__ B1t,
             const short* __restrict__ B2t, void* __restrict__ Cout,
             int M, int N, int K,
             const int* __restrict__ counts, const int* __restrict__ base,
             const int* __restrict__ row_token, const float* __restrict__ row_wgt,
             const int* __restrict__ tile_e, const int* __restrict__ tile_m0) {
    int e = 0, m0, Mrows, rowbase = 0;
    if (WL) {
        e = tile_e[blockIdx.y];
        if (e < 0) return;
        m0 = tile_m0[blockIdx.y];
        Mrows = counts[e];
        rowbase = base[e];
    } else {
        m0 = blockIdx.y * 128;
        Mrows = M;
    }
    int n0 = blockIdx.x * 128;
    const short* B1 = B1t + (WL ? (size_t)e * N * K : 0) + (size_t)n0 * K;
    const short* B2 = FUSED ? (B2t + (WL ? (size_t)e * N * K : 0) + (size_t)n0 * K) : nullptr;

    __shared__ short As[3 * 4096];                    // 3 x 128x32
    __shared__ short Bs1[3 * 4096];
    __shared__ short Bs2[FUSED ? 3 * 4096 : 16];

    int tid = threadIdx.x;
    int lane = tid & 63, w = tid >> 6;
    int wr = w >> 1, wc = w & 1;
    int quad = lane >> 4, l16 = lane & 15;
    int sr = lane >> 2, sc = lane & 3;

    const short* aptr[2];
    const short* b1ptr[2];
    const short* b2ptr[2];
    #pragma unroll
    for (int i = 0; i < 2; i++) {
        int row = w * 32 + i * 16 + sr;
        int mrow = m0 + row;
        int cl = mrow < Mrows ? mrow : (Mrows - 1);
        size_t arow;
        if (GATHER)  arow = (size_t)row_token[rowbase + cl];
        else if (WL) arow = (size_t)(rowbase + cl);
        else         arow = (size_t)mrow;
        aptr[i] = A + arow * K + sc * 8;
        b1ptr[i] = B1 + (size_t)row * K + sc * 8;
        if (FUSED) b2ptr[i] = B2 + (size_t)row * K + sc * 8;
    }

    f32x4 acc1[4][4] = {};
    f32x4 acc2[4][4] = {};

    const int nk = K >> 5;
    auto stage = [&](int slot) {
        #pragma unroll
        for (int i = 0; i < 2; i++) {
            int lb = slot * 4096 + (w * 32 + i * 16) * 32;
            gl2lds16(aptr[i], &As[lb]);   aptr[i] += 32;
            gl2lds16(b1ptr[i], &Bs1[lb]); b1ptr[i] += 32;
            if (FUSED) { gl2lds16(b2ptr[i], &Bs2[lb]); b2ptr[i] += 32; }
        }
    };
    stage(0);
    if (nk > 1) stage(1);

    int slot = 0, nslot = 2;
    for (int t = 0; t < nk; t++) {
        // wait for stage t only: leave the 1 in-flight stage (6 or 4 loads) pending
        if (t + 1 < nk) {
            if constexpr (FUSED) asm volatile("s_waitcnt vmcnt(6)" ::: "memory");
            else                 asm volatile("s_waitcnt vmcnt(4)" ::: "memory");
        } else {
            asm volatile("s_waitcnt vmcnt(0)" ::: "memory");
        }
        __builtin_amdgcn_s_barrier();
        __builtin_amdgcn_sched_barrier(0);   // nothing crosses the barrier (rule #18)

        if (t + 2 < nk) stage(nslot);

        int bofs = slot * 4096;
        short8 a[4], b1[4], b2[4];
        #pragma unroll
        for (int i = 0; i < 4; i++)
            a[i] = *(const short8*)&As[bofs + (wr * 64 + i * 16 + l16) * 32 + quad * 8];
        #pragma unroll
        for (int j = 0; j < 4; j++) {
            b1[j] = *(const short8*)&Bs1[bofs + (wc * 64 + j * 16 + l16) * 32 + quad * 8];
            if (FUSED)
                b2[j] = *(const short8*)&Bs2[bofs + (wc * 64 + j * 16 + l16) * 32 + quad * 8];
        }
        #pragma unroll
        for (int i = 0; i < 4; i++)
            #pragma unroll
            for (int j = 0; j < 4; j++) {
                acc1[i][j] = __builtin_amdgcn_mfma_f32_16x16x32_bf16(a[i], b1[j], acc1[i][j], 0, 0, 0);
                if (FUSED)
                    acc2[i][j] = __builtin_amdgcn_mfma_f32_16x16x32_bf16(a[i], b2[j], acc2[i][j], 0, 0, 0);
            }
        slot = (slot == 2) ? 0 : slot + 1;
        nslot = (nslot == 2) ? 0 : nslot + 1;
    }

    #pragma unroll
    for (int i = 0; i < 4; i++) {
        #pragma unroll
        for (int rr = 0; rr < 4; rr++) {
            int row = m0 + wr * 64 + i * 16 + quad * 4 + rr;
            if (row >= Mrows) continue;
            size_t orow = WL ? (size_t)(rowbase + row) : (size_t)row;
            float scl = 0.f;
            if (EPI == 2) scl = row_wgt[rowbase + row];
            #pragma unroll
            for (int j = 0; j < 4; j++) {
                int n = n0 + wc * 64 + j * 16 + l16;
                float v = acc1[i][j][rr];
                if (EPI == 0) {
                    float u = acc2[i][j][rr];
                    float h = v / (1.f + __expf(-v)) * u;
                    ((unsigned short*)Cout)[orow * N + n] = f2bf(h);
                } else if (EPI == 1) {
                    ((float*)Cout)[orow * N + n] = v;
                } else {
                    ((float*)Cout)[orow * N + n] = v * scl;
                }
            }
        }
    }
}

// ---------------- launch ----------------
extern "C" void kernel_launch(void* const* d_in, const int* in_sizes, int n_in,
                              void* d_out, int out_size, void* d_ws, size_t ws_size,
                              hipStream_t stream) {
    const float* x        = (const float*)d_in[0];
    const float* router_w = (const float*)d_in[1];
    const float* e_bias   = (const float*)d_in[2];
    const float* gate_w   = (const float*)d_in[3];
    const float* up_w     = (const float*)d_in[4];
    const float* down_w   = (const float*)d_in[5];
    const float* sh_gate  = (const float*)d_in[6];
    const float* sh_up    = (const float*)d_in[7];
    const float* sh_down  = (const float*)d_in[8];
    float* out = (float*)d_out;
    char* ws = (char*)d_ws;

    int*   counts    = (int*)(ws);
    int*   base      = (int*)(ws + 256);
    int*   cursor    = (int*)(ws + 512);
    int*   topk_idx  = (int*)(ws + 1024);
    float* topk_w    = (float*)(ws + 1024 + 131072);
    int*   row_token = (int*)(ws + 1024 + 2 * 131072);
    float* row_wgt   = (float*)(ws + 1024 + 3 * 131072);
    float* scoresbuf = (float*)(ws + 1024 + 4 * 131072);           // 1 MB
    int*   pos_of    = (int*)(ws + 1664 * 1024);                   // 128 KB
    int*   tile_e    = (int*)(ws + 1800 * 1024);                   // 1.25 KB
    int*   tile_m0   = (int*)(ws + 1808 * 1024);                   // 1.25 KB
    const size_t MB = 1u << 20;
    unsigned short* xb        = (unsigned short*)(ws + 2 * MB);    // 8 MB
    unsigned short* Hs        = (unsigned short*)(ws + 10 * MB);   // 16 MB
    unsigned short* Hr        = (unsigned short*)(ws + 26 * MB);   // 32 MB
    unsigned short* sh_gate_t = (unsigned short*)(ws + 58 * MB);   // 4 MB
    unsigned short* sh_up_t   = (unsigned short*)(ws + 62 * MB);   // 4 MB
    unsigned short* sh_down_t = (unsigned short*)(ws + 66 * MB);   // 4 MB
    unsigned short* gate_t    = (unsigned short*)(ws + 70 * MB);   // 64 MB
    unsigned short* up_t      = (unsigned short*)(ws + 134 * MB);  // 64 MB
    unsigned short* down_t    = (unsigned short*)(ws + 198 * MB);  // 64 MB -> 262 MB
    // O overlays gate_t+up_t (dead after routed fused GEMM): 32768x1024 f32 = 128 MiB
    float* O = (float*)(ws + 70 * MB);

    // ---- routing ----
    zero_counts_k<<<1, 64, 0, stream>>>(counts);
    router_scores_k<<<S_TOK / 32, 256, 0, stream>>>(x, router_w, scoresbuf);
    topk_k<<<S_TOK / 4, 256, 0, stream>>>(scoresbuf, e_bias, topk_idx, topk_w, counts);
    scan_k<<<1, 64, 0, stream>>>(counts, base, cursor, tile_e, tile_m0);
    scatter_k<<<ROWS_TOTAL / 256, 256, 0, stream>>>(topk_idx, topk_w, cursor, row_token, row_wgt, pos_of);

    // ---- prepass: bf16 conversion + weight transposes ----
    cvt_bf16_k<<<S_TOK * C_DIM / 8 / 256, 256, 0, stream>>>(x, xb, S_TOK * C_DIM / 8);
    transpose_k<<<dim3(HS_DIM / 64, C_DIM / 64, 1), 256, 0, stream>>>(sh_gate, sh_gate_t, C_DIM, HS_DIM);
    transpose_k<<<dim3(HS_DIM / 64, C_DIM / 64, 1), 256, 0, stream>>>(sh_up,   sh_up_t,   C_DIM, HS_DIM);
    transpose_k<<<dim3(C_DIM / 64, HS_DIM / 64, 1), 256, 0, stream>>>(sh_down, sh_down_t, HS_DIM, C_DIM);
    transpose_k<<<dim3(H_DIM / 64, C_DIM / 64, E_NUM), 256, 0, stream>>>(gate_w, gate_t, C_DIM, H_DIM);
    transpose_k<<<dim3(H_DIM / 64, C_DIM / 64, E_NUM), 256, 0, stream>>>(up_w,   up_t,   C_DIM, H_DIM);
    transpose_k<<<dim3(C_DIM / 64, H_DIM / 64, E_NUM), 256, 0, stream>>>(down_w, down_t, H_DIM, C_DIM);

    // ---- shared expert ----
    gemm2_k<true, false, false, 0><<<dim3(HS_DIM / 128, S_TOK / 128, 1), 256, 0, stream>>>(
        (const short*)xb, (const short*)sh_gate_t, (const short*)sh_up_t, Hs,
        S_TOK, HS_DIM, C_DIM, nullptr, nullptr, nullptr, nullptr, nullptr, nullptr);
    gemm2_k<false, false, false, 1><<<dim3(C_DIM / 128, S_TOK / 128, 1), 256, 0, stream>>>(
        (const short*)Hs, (const short*)sh_down_t, nullptr, out,
        S_TOK, C_DIM, HS_DIM, nullptr, nullptr, nullptr, nullptr, nullptr, nullptr);

    // ---- routed experts (worklist-balanced) ----
    gemm2_k<true, true, true, 0><<<dim3(H_DIM / 128, T_TILES, 1), 256, 0, stream>>>(
        (const short*)xb, (const short*)gate_t, (const short*)up_t, Hr,
        0, H_DIM, C_DIM, counts, base, row_token, row_wgt, tile_e, tile_m0);
    gemm2_k<false, false, true, 2><<<dim3(C_DIM / 128, T_TILES, 1), 256, 0, stream>>>(
        (const short*)Hr, (const short*)down_t, nullptr, O,
        0, C_DIM, H_DIM, counts, base, row_token, row_wgt, tile_e, tile_m0);

    // ---- combine routed into out (out already holds shared-expert result) ----
    combine_k<<<S_TOK, 256, 0, stream>>>(O, pos_of, out);
}

// Round 4
// 940.899 us; speedup vs baseline: 1.0839x; 1.0097x over previous
//
#include <hip/hip_runtime.h>
#include <hip/hip_bf16.h>
#include <stdint.h>

// MoE FFN: sigmoid router (group-limited greedy top-8 of 64), SwiGLU experts
// (1024->512->1024) + shared expert (1024->2048->1024). All inputs fp32.
// R7: fused GEMM tile 128x128 -> 128x64 (wave-tile 64x32, acc 64 regs,
// LDS 48 KB) so 3 blocks/CU fit (was 2: 72 KB LDS + 224 combined VGPR).
// Non-fused pinned to 3 blocks/CU via launch_bounds. zero_counts folded
// into router_scores_k. Worklist + 3-slot ring + counted vmcnt kept (R5/R6).

#define S_TOK 4096
#define C_DIM 1024
#define E_NUM 64
#define H_DIM 512
#define HS_DIM 2048
#define ROWS_TOTAL (S_TOK * 8)
#define T_TILES 320   // ROWS_TOTAL/128 + E_NUM upper bound on routed m-tiles

typedef __attribute__((ext_vector_type(8))) short short8;
typedef __attribute__((ext_vector_type(4))) float f32x4;

static __device__ __forceinline__ unsigned short f2bf(float f) {
    union { float f; uint32_t u; } v; v.f = f;
    uint32_t u = v.u;
    u += 0x7fffu + ((u >> 16) & 1u);   // RNE
    return (unsigned short)(u >> 16);
}

static __device__ __forceinline__ void gl2lds16(const void* g, void* l) {
    __builtin_amdgcn_global_load_lds(
        (const __attribute__((address_space(1))) uint32_t*)g,
        (__attribute__((address_space(3))) uint32_t*)l, 16, 0, 0);
}

// ---------------- router part 1: scores = sigmoid(x @ rw^T), fp32 ----------------
__global__ __launch_bounds__(256)
void router_scores_k(const float* __restrict__ x, const float* __restrict__ rw,
                     float* __restrict__ scores, int* __restrict__ counts) {
    if (blockIdx.x == 0 && threadIdx.x < E_NUM) counts[threadIdx.x] = 0;
    int t0 = blockIdx.x * 32;
    __shared__ float xs[32][36];
    __shared__ float wsm[64][36];
    int t = threadIdx.x;
    int tx = t & 15, ty = t >> 4;
    float acc[2][4] = {};
    for (int k0 = 0; k0 < C_DIM; k0 += 32) {
        {
            int r = t >> 3, c = t & 7;
            *(float4*)&xs[r][c * 4] = *(const float4*)(x + (size_t)(t0 + r) * C_DIM + k0 + c * 4);
        }
        #pragma unroll
        for (int i = 0; i < 2; i++) {
            int idx = t + 256 * i;
            int r = idx >> 3, c = idx & 7;
            *(float4*)&wsm[r][c * 4] = *(const float4*)(rw + (size_t)r * C_DIM + k0 + c * 4);
        }
        __syncthreads();
        #pragma unroll
        for (int kk = 0; kk < 32; kk += 4) {
            float4 a0 = *(const float4*)&xs[ty * 2 + 0][kk];
            float4 a1 = *(const float4*)&xs[ty * 2 + 1][kk];
            #pragma unroll
            for (int j = 0; j < 4; j++) {
                float4 b = *(const float4*)&wsm[tx * 4 + j][kk];
                acc[0][j] += a0.x * b.x + a0.y * b.y + a0.z * b.z + a0.w * b.w;
                acc[1][j] += a1.x * b.x + a1.y * b.y + a1.z * b.z + a1.w * b.w;
            }
        }
        __syncthreads();
    }
    #pragma unroll
    for (int i = 0; i < 2; i++)
        #pragma unroll
        for (int j = 0; j < 4; j++)
            scores[(size_t)(t0 + ty * 2 + i) * E_NUM + tx * 4 + j] =
                1.f / (1.f + __expf(-acc[i][j]));
}

// ---------------- router part 2: wave-parallel grouped top-k ----------------
__global__ __launch_bounds__(256)
void topk_k(const float* __restrict__ scores, const float* __restrict__ ebias,
            int* __restrict__ topk_idx, float* __restrict__ topk_w,
            int* __restrict__ counts) {
    int t = blockIdx.x * 4 + (threadIdx.x >> 6);
    int e = threadIdx.x & 63;
    float sc = scores[(size_t)t * E_NUM + e];
    float sb = sc + ebias[e];
    float m1 = sb, m2 = -1e30f;
    #pragma unroll
    for (int off = 1; off <= 4; off <<= 1) {
        float o1 = __shfl_xor(m1, off);
        float o2 = __shfl_xor(m2, off);
        float hi = fmaxf(m1, o1), lo = fminf(m1, o1);
        m2 = fmaxf(lo, fmaxf(m2, o2));
        m1 = hi;
    }
    float grp = m1 + m2;
    float grpv[8];
    #pragma unroll
    for (int g = 0; g < 8; g++) grpv[g] = __shfl(grp, g * 8);
    unsigned gsel = 0;
    #pragma unroll
    for (int k = 0; k < 4; k++) {
        float best = -1e30f; int bi = 0;
        #pragma unroll
        for (int g = 0; g < 8; g++)
            if (!((gsel >> g) & 1) && grpv[g] > best) { best = grpv[g]; bi = g; }
        gsel |= 1u << bi;
    }
    float val = ((gsel >> (e >> 3)) & 1) ? sb : -1e30f;
    int idx[8]; float sv[8]; float wsum = 0.f;
    #pragma unroll
    for (int k = 0; k < 8; k++) {
        uint32_t u = __float_as_uint(val);
        uint32_t mu = (u & 0x80000000u) ? ~u : (u | 0x80000000u);
        unsigned long long key = ((unsigned long long)mu << 6) | (unsigned long long)(63 - e);
        #pragma unroll
        for (int off = 32; off; off >>= 1) {
            unsigned long long ok = __shfl_xor(key, off);
            if (ok > key) key = ok;
        }
        int win = 63 - (int)(key & 63ull);
        idx[k] = win;
        sv[k] = __shfl(sc, win);
        wsum += sv[k];
        if (e == win) val = -1e30f;
    }
    float inv = 1.f / (wsum + 1e-20f);
    if (e < 8) {
        topk_idx[t * 8 + e] = idx[e];
        topk_w[t * 8 + e] = sv[e] * inv;
        atomicAdd(&counts[idx[e]], 1);
    }
}

// exclusive scan over 64 expert counts + m-tile worklist build, one wave
__global__ void scan_k(const int* __restrict__ counts, int* __restrict__ base,
                       int* __restrict__ cursor, int* __restrict__ tile_e,
                       int* __restrict__ tile_m0) {
    int e = threadIdx.x;
    int c = counts[e];
    int s = c;
    #pragma unroll
    for (int off = 1; off < 64; off <<= 1) {
        int o = __shfl_up(s, off);
        if (e >= off) s += o;
    }
    int ex = s - c;
    base[e] = ex;
    cursor[e] = ex;
    int nt = (c + 127) >> 7;
    int ts = nt;
    #pragma unroll
    for (int off = 1; off < 64; off <<= 1) {
        int o = __shfl_up(ts, off);
        if (e >= off) ts += o;
    }
    int tb = ts - nt;
    for (int i = 0; i < nt; i++) { tile_e[tb + i] = e; tile_m0[tb + i] = i * 128; }
    int total = __shfl(ts, 63);
    for (int j = total + e; j < T_TILES; j += 64) tile_e[j] = -1;
}

__global__ void scatter_k(const int* __restrict__ topk_idx, const float* __restrict__ topk_w,
                          int* __restrict__ cursor, int* __restrict__ row_token,
                          float* __restrict__ row_wgt, int* __restrict__ pos_of) {
    int i = blockIdx.x * blockDim.x + threadIdx.x;
    int e = topk_idx[i];
    int pos = atomicAdd(&cursor[e], 1);
    row_token[pos] = i >> 3;
    row_wgt[pos] = topk_w[i];
    pos_of[i] = pos;
}

// ---------------- combine: out[t] += sum_k O[pos_of[t*8+k]] (weights pre-applied) ---
__global__ __launch_bounds__(256)
void combine_k(const float* __restrict__ O, const int* __restrict__ pos_of,
               float* __restrict__ out) {
    int t = blockIdx.x;
    int c = threadIdx.x;
    float4 s = ((const float4*)(out + (size_t)t * C_DIM))[c];
    int p[8];
    #pragma unroll
    for (int k = 0; k < 8; k++) p[k] = pos_of[t * 8 + k];
    #pragma unroll
    for (int k = 0; k < 8; k++) {
        float4 v = ((const float4*)(O + (size_t)p[k] * C_DIM))[c];
        s.x += v.x; s.y += v.y; s.z += v.z; s.w += v.w;
    }
    ((float4*)(out + (size_t)t * C_DIM))[c] = s;
}

// ---------------- prepass: fp32 -> bf16 elementwise (x) ----------------
__global__ void cvt_bf16_k(const float* __restrict__ in, unsigned short* __restrict__ out, int n8) {
    int i = blockIdx.x * blockDim.x + threadIdx.x;
    if (i >= n8) return;
    float4 v0 = ((const float4*)in)[2 * i];
    float4 v1 = ((const float4*)in)[2 * i + 1];
    unsigned short t[8] = { f2bf(v0.x), f2bf(v0.y), f2bf(v0.z), f2bf(v0.w),
                            f2bf(v1.x), f2bf(v1.y), f2bf(v1.z), f2bf(v1.w) };
    ((uint4*)out)[i] = *(uint4*)t;
}

// ---------------- prepass: fp32 [R][C] -> bf16 [C][R], batched over z ----------------
#define TP 69
__global__ __launch_bounds__(256)
void transpose_k(const float* __restrict__ in, unsigned short* __restrict__ out, int R, int C) {
    size_t bofs = (size_t)blockIdx.z * R * C;
    in += bofs; out += bofs;
    int r0 = blockIdx.y * 64, c0 = blockIdx.x * 64;
    __shared__ float T[64 * TP];
    int t = threadIdx.x;
    int cg = t & 15, rg = t >> 4;
    #pragma unroll
    for (int ii = 0; ii < 4; ii++) {
        float4 v = *(const float4*)(in + (size_t)(r0 + rg * 4 + ii) * C + c0 + cg * 4);
        T[(cg * 4 + 0) * TP + rg * 4 + ii] = v.x;
        T[(cg * 4 + 1) * TP + rg * 4 + ii] = v.y;
        T[(cg * 4 + 2) * TP + rg * 4 + ii] = v.z;
        T[(cg * 4 + 3) * TP + rg * 4 + ii] = v.w;
    }
    __syncthreads();
    int n = t >> 2, ks = (t & 3) * 16;
    unsigned short h[16];
    #pragma unroll
    for (int u = 0; u < 16; u++) h[u] = f2bf(T[n * TP + ks + u]);
    unsigned short* op = out + (size_t)(c0 + n) * R + r0 + ks;
    *(uint4*)op = *(uint4*)&h[0];
    *(uint4*)(op + 8) = *(uint4*)&h[8];
}

// ---------------- GEMM: C[M,N] = A[M,K] @ Bt[N,K]^T, bf16 in, fp32 acc ----------------
// FUSED: tile 128x64 (wave 64x32, acc1+acc2 = 64 regs, LDS 48 KB, 3 blocks/CU)
// non-FUSED: tile 128x128 (wave 64x64, acc 64 regs, LDS 48 KB, 3 blocks/CU)
// 3-slot LDS ring, 2-deep prefetch, counted vmcnt(4) + raw barriers.
// EPI: 0 = SwiGLU(acc1)*acc2 -> bf16; 1 = f32 store; 2 = f32 scaled store
template<bool FUSED, bool GATHER, bool WL, int EPI>
__global__ __launch_bounds__(256, 3)
void gemm2_k(const short* __restrict__ A, const short* __restrict__ B1t,
             const short* __restrict__ B2t, void* __restrict__ Cout,
             int M, int N, int K,
             const int* __restrict__ counts, const int* __restrict__ base,
             const int* __restrict__ row_token, const float* __restrict__ row_wgt,
             const int* __restrict__ tile_e, const int* __restrict__ tile_m0) {
    constexpr int BN = FUSED ? 64 : 128;
    constexpr int NJ = FUSED ? 2 : 4;

    int e = 0, m0, Mrows, rowbase = 0;
    if (WL) {
        e = tile_e[blockIdx.y];
        if (e < 0) return;
        m0 = tile_m0[blockIdx.y];
        Mrows = counts[e];
        rowbase = base[e];
    } else {
        m0 = blockIdx.y * 128;
        Mrows = M;
    }
    int n0 = blockIdx.x * BN;
    const short* B1 = B1t + (WL ? (size_t)e * N * K : 0) + (size_t)n0 * K;
    const short* B2 = FUSED ? (B2t + (WL ? (size_t)e * N * K : 0) + (size_t)n0 * K) : nullptr;

    __shared__ short As[3 * 4096];                       // 3 x 128x32
    __shared__ short Bs1[FUSED ? 3 * 2048 : 3 * 4096];   // 3 x BNx32
    __shared__ short Bs2[FUSED ? 3 * 2048 : 16];

    int tid = threadIdx.x;
    int lane = tid & 63, w = tid >> 6;
    int wr = w >> 1, wc = w & 1;
    int quad = lane >> 4, l16 = lane & 15;
    int sr = lane >> 2, sc = lane & 3;

    const short* aptr[2];
    const short* b1ptr[2];
    const short* b2ptr;
    #pragma unroll
    for (int i = 0; i < 2; i++) {
        int row = w * 32 + i * 16 + sr;
        int mrow = m0 + row;
        int cl = mrow < Mrows ? mrow : (Mrows - 1);
        size_t arow;
        if (GATHER)  arow = (size_t)row_token[rowbase + cl];
        else if (WL) arow = (size_t)(rowbase + cl);
        else         arow = (size_t)mrow;
        aptr[i] = A + arow * K + sc * 8;
    }
    if constexpr (FUSED) {
        int row = w * 16 + sr;                 // 4 waves cover 64 B-rows
        b1ptr[0] = B1 + (size_t)row * K + sc * 8;
        b2ptr    = B2 + (size_t)row * K + sc * 8;
    } else {
        #pragma unroll
        for (int i = 0; i < 2; i++) {
            int row = w * 32 + i * 16 + sr;
            b1ptr[i] = B1 + (size_t)row * K + sc * 8;
        }
        b2ptr = nullptr;
    }

    f32x4 acc1[4][NJ] = {};
    f32x4 acc2[FUSED ? 4 : 1][NJ] = {};

    const int nk = K >> 5;
    auto stage = [&](int slot) {
        #pragma unroll
        for (int i = 0; i < 2; i++) {
            gl2lds16(aptr[i], &As[slot * 4096 + (w * 32 + i * 16) * 32]);
            aptr[i] += 32;
        }
        if constexpr (FUSED) {
            gl2lds16(b1ptr[0], &Bs1[slot * 2048 + w * 512]); b1ptr[0] += 32;
            gl2lds16(b2ptr,    &Bs2[slot * 2048 + w * 512]); b2ptr += 32;
        } else {
            #pragma unroll
            for (int i = 0; i < 2; i++) {
                gl2lds16(b1ptr[i], &Bs1[slot * 4096 + (w * 32 + i * 16) * 32]);
                b1ptr[i] += 32;
            }
        }
    };
    stage(0);
    if (nk > 1) stage(1);

    int slot = 0, nslot = 2;
    for (int t = 0; t < nk; t++) {
        // wait for stage t only: leave the 1 in-flight stage (4 loads/wave) pending
        if (t + 1 < nk) {
            asm volatile("s_waitcnt vmcnt(4)" ::: "memory");
        } else {
            asm volatile("s_waitcnt vmcnt(0)" ::: "memory");
        }
        __builtin_amdgcn_s_barrier();
        __builtin_amdgcn_sched_barrier(0);   // nothing crosses the barrier (rule #18)

        if (t + 2 < nk) stage(nslot);

        short8 a[4], b1[NJ], b2[NJ];
        #pragma unroll
        for (int i = 0; i < 4; i++)
            a[i] = *(const short8*)&As[slot * 4096 + (wr * 64 + i * 16 + l16) * 32 + quad * 8];
        if constexpr (FUSED) {
            #pragma unroll
            for (int j = 0; j < NJ; j++) {
                b1[j] = *(const short8*)&Bs1[slot * 2048 + (wc * 32 + j * 16 + l16) * 32 + quad * 8];
                b2[j] = *(const short8*)&Bs2[slot * 2048 + (wc * 32 + j * 16 + l16) * 32 + quad * 8];
            }
        } else {
            #pragma unroll
            for (int j = 0; j < NJ; j++)
                b1[j] = *(const short8*)&Bs1[slot * 4096 + (wc * 64 + j * 16 + l16) * 32 + quad * 8];
        }
        #pragma unroll
        for (int i = 0; i < 4; i++)
            #pragma unroll
            for (int j = 0; j < NJ; j++) {
                acc1[i][j] = __builtin_amdgcn_mfma_f32_16x16x32_bf16(a[i], b1[j], acc1[i][j], 0, 0, 0);
                if (FUSED)
                    acc2[i][j] = __builtin_amdgcn_mfma_f32_16x16x32_bf16(a[i], b2[j], acc2[i][j], 0, 0, 0);
            }
        slot = (slot == 2) ? 0 : slot + 1;
        nslot = (nslot == 2) ? 0 : nslot + 1;
    }

    constexpr int CB = FUSED ? 32 : 64;
    #pragma unroll
    for (int i = 0; i < 4; i++) {
        #pragma unroll
        for (int rr = 0; rr < 4; rr++) {
            int row = m0 + wr * 64 + i * 16 + quad * 4 + rr;
            if (row >= Mrows) continue;
            size_t orow = WL ? (size_t)(rowbase + row) : (size_t)row;
            float scl = 0.f;
            if (EPI == 2) scl = row_wgt[rowbase + row];
            #pragma unroll
            for (int j = 0; j < NJ; j++) {
                int n = n0 + wc * CB + j * 16 + l16;
                float v = acc1[i][j][rr];
                if (EPI == 0) {
                    float u = acc2[i][j][rr];
                    float h = v / (1.f + __expf(-v)) * u;
                    ((unsigned short*)Cout)[orow * N + n] = f2bf(h);
                } else if (EPI == 1) {
                    ((float*)Cout)[orow * N + n] = v;
                } else {
                    ((float*)Cout)[orow * N + n] = v * scl;
                }
            }
        }
    }
}

// ---------------- launch ----------------
extern "C" void kernel_launch(void* const* d_in, const int* in_sizes, int n_in,
                              void* d_out, int out_size, void* d_ws, size_t ws_size,
                              hipStream_t stream) {
    const float* x        = (const float*)d_in[0];
    const float* router_w = (const float*)d_in[1];
    const float* e_bias   = (const float*)d_in[2];
    const float* gate_w   = (const float*)d_in[3];
    const float* up_w     = (const float*)d_in[4];
    const float* down_w   = (const float*)d_in[5];
    const float* sh_gate  = (const float*)d_in[6];
    const float* sh_up    = (const float*)d_in[7];
    const float* sh_down  = (const float*)d_in[8];
    float* out = (float*)d_out;
    char* ws = (char*)d_ws;

    int*   counts    = (int*)(ws);
    int*   base      = (int*)(ws + 256);
    int*   cursor    = (int*)(ws + 512);
    int*   topk_idx  = (int*)(ws + 1024);
    float* topk_w    = (float*)(ws + 1024 + 131072);
    int*   row_token = (int*)(ws + 1024 + 2 * 131072);
    float* row_wgt   = (float*)(ws + 1024 + 3 * 131072);
    float* scoresbuf = (float*)(ws + 1024 + 4 * 131072);           // 1 MB
    int*   pos_of    = (int*)(ws + 1664 * 1024);                   // 128 KB
    int*   tile_e    = (int*)(ws + 1800 * 1024);                   // 1.25 KB
    int*   tile_m0   = (int*)(ws + 1808 * 1024);                   // 1.25 KB
    const size_t MB = 1u << 20;
    unsigned short* xb        = (unsigned short*)(ws + 2 * MB);    // 8 MB
    unsigned short* Hs        = (unsigned short*)(ws + 10 * MB);   // 16 MB
    unsigned short* Hr        = (unsigned short*)(ws + 26 * MB);   // 32 MB
    unsigned short* sh_gate_t = (unsigned short*)(ws + 58 * MB);   // 4 MB
    unsigned short* sh_up_t   = (unsigned short*)(ws + 62 * MB);   // 4 MB
    unsigned short* sh_down_t = (unsigned short*)(ws + 66 * MB);   // 4 MB
    unsigned short* gate_t    = (unsigned short*)(ws + 70 * MB);   // 64 MB
    unsigned short* up_t      = (unsigned short*)(ws + 134 * MB);  // 64 MB
    unsigned short* down_t    = (unsigned short*)(ws + 198 * MB);  // 64 MB -> 262 MB
    // O overlays gate_t+up_t (dead after routed fused GEMM): 32768x1024 f32 = 128 MiB
    float* O = (float*)(ws + 70 * MB);

    // ---- routing ----
    router_scores_k<<<S_TOK / 32, 256, 0, stream>>>(x, router_w, scoresbuf, counts);
    topk_k<<<S_TOK / 4, 256, 0, stream>>>(scoresbuf, e_bias, topk_idx, topk_w, counts);
    scan_k<<<1, 64, 0, stream>>>(counts, base, cursor, tile_e, tile_m0);
    scatter_k<<<ROWS_TOTAL / 256, 256, 0, stream>>>(topk_idx, topk_w, cursor, row_token, row_wgt, pos_of);

    // ---- prepass: bf16 conversion + weight transposes ----
    cvt_bf16_k<<<S_TOK * C_DIM / 8 / 256, 256, 0, stream>>>(x, xb, S_TOK * C_DIM / 8);
    transpose_k<<<dim3(HS_DIM / 64, C_DIM / 64, 1), 256, 0, stream>>>(sh_gate, sh_gate_t, C_DIM, HS_DIM);
    transpose_k<<<dim3(HS_DIM / 64, C_DIM / 64, 1), 256, 0, stream>>>(sh_up,   sh_up_t,   C_DIM, HS_DIM);
    transpose_k<<<dim3(C_DIM / 64, HS_DIM / 64, 1), 256, 0, stream>>>(sh_down, sh_down_t, HS_DIM, C_DIM);
    transpose_k<<<dim3(H_DIM / 64, C_DIM / 64, E_NUM), 256, 0, stream>>>(gate_w, gate_t, C_DIM, H_DIM);
    transpose_k<<<dim3(H_DIM / 64, C_DIM / 64, E_NUM), 256, 0, stream>>>(up_w,   up_t,   C_DIM, H_DIM);
    transpose_k<<<dim3(C_DIM / 64, H_DIM / 64, E_NUM), 256, 0, stream>>>(down_w, down_t, H_DIM, C_DIM);

    // ---- shared expert ----
    gemm2_k<true, false, false, 0><<<dim3(HS_DIM / 64, S_TOK / 128, 1), 256, 0, stream>>>(
        (const short*)xb, (const short*)sh_gate_t, (const short*)sh_up_t, Hs,
        S_TOK, HS_DIM, C_DIM, nullptr, nullptr, nullptr, nullptr, nullptr, nullptr);
    gemm2_k<false, false, false, 1><<<dim3(C_DIM / 128, S_TOK / 128, 1), 256, 0, stream>>>(
        (const short*)Hs, (const short*)sh_down_t, nullptr, out,
        S_TOK, C_DIM, HS_DIM, nullptr, nullptr, nullptr, nullptr, nullptr, nullptr);

    // ---- routed experts (worklist-balanced) ----
    gemm2_k<true, true, true, 0><<<dim3(H_DIM / 64, T_TILES, 1), 256, 0, stream>>>(
        (const short*)xb, (const short*)gate_t, (const short*)up_t, Hr,
        0, H_DIM, C_DIM, counts, base, row_token, row_wgt, tile_e, tile_m0);
    gemm2_k<false, false, true, 2><<<dim3(C_DIM / 128, T_TILES, 1), 256, 0, stream>>>(
        (const short*)Hr, (const short*)down_t, nullptr, O,
        0, C_DIM, H_DIM, counts, base, row_token, row_wgt, tile_e, tile_m0);

    // ---- combine routed into out (out already holds shared-expert result) ----
    combine_k<<<S_TOK, 256, 0, stream>>>(O, pos_of, out);
}

// Round 5
// 881.353 us; speedup vs baseline: 1.1572x; 1.0676x over previous
//
#include <hip/hip_runtime.h>
#include <hip/hip_bf16.h>
#include <stdint.h>

// MoE FFN: sigmoid router (group-limited greedy top-8 of 64), SwiGLU experts
// (1024->512->1024) + shared expert (1024->2048->1024). All inputs fp32.
// R8: weight TRANSPOSE KERNELS DELETED (~576 MB/iter of pure layout traffic).
// GEMM B-staging now reads native fp32 [K][N] weights directly: 16 coalesced
// dword loads/thread gathering 8 k's per column, in-register f2bf (same RNE
// -> bitwise-identical results), short8 store into the [N][K] LDS tile with
// a 2-bit XOR swizzle on BOTH write and read (2-way writes = free, reads
// exact-cover conflict-free). B rides registers (latency hidden under MFMA),
// A keeps global_load_lds; plain 2-buffer __syncthreads loop (counted vmcnt
// dropped - B loads would pollute the count). LDS 48->32 KB.
// Worklist balancing (R6) + combine-not-atomics (R5) kept.

#define S_TOK 4096
#define C_DIM 1024
#define E_NUM 64
#define H_DIM 512
#define HS_DIM 2048
#define ROWS_TOTAL (S_TOK * 8)
#define T_TILES 320   // ROWS_TOTAL/128 + E_NUM upper bound on routed m-tiles

typedef __attribute__((ext_vector_type(8))) short short8;
typedef __attribute__((ext_vector_type(4))) float f32x4;

static __device__ __forceinline__ unsigned short f2bf(float f) {
    union { float f; uint32_t u; } v; v.f = f;
    uint32_t u = v.u;
    u += 0x7fffu + ((u >> 16) & 1u);   // RNE
    return (unsigned short)(u >> 16);
}

static __device__ __forceinline__ void gl2lds16(const void* g, void* l) {
    __builtin_amdgcn_global_load_lds(
        (const __attribute__((address_space(1))) uint32_t*)g,
        (__attribute__((address_space(3))) uint32_t*)l, 16, 0, 0);
}

// ---------------- router part 1: scores = sigmoid(x @ rw^T), fp32 ----------------
__global__ __launch_bounds__(256)
void router_scores_k(const float* __restrict__ x, const float* __restrict__ rw,
                     float* __restrict__ scores, int* __restrict__ counts) {
    if (blockIdx.x == 0 && threadIdx.x < E_NUM) counts[threadIdx.x] = 0;
    int t0 = blockIdx.x * 32;
    __shared__ float xs[32][36];
    __shared__ float wsm[64][36];
    int t = threadIdx.x;
    int tx = t & 15, ty = t >> 4;
    float acc[2][4] = {};
    for (int k0 = 0; k0 < C_DIM; k0 += 32) {
        {
            int r = t >> 3, c = t & 7;
            *(float4*)&xs[r][c * 4] = *(const float4*)(x + (size_t)(t0 + r) * C_DIM + k0 + c * 4);
        }
        #pragma unroll
        for (int i = 0; i < 2; i++) {
            int idx = t + 256 * i;
            int r = idx >> 3, c = idx & 7;
            *(float4*)&wsm[r][c * 4] = *(const float4*)(rw + (size_t)r * C_DIM + k0 + c * 4);
        }
        __syncthreads();
        #pragma unroll
        for (int kk = 0; kk < 32; kk += 4) {
            float4 a0 = *(const float4*)&xs[ty * 2 + 0][kk];
            float4 a1 = *(const float4*)&xs[ty * 2 + 1][kk];
            #pragma unroll
            for (int j = 0; j < 4; j++) {
                float4 b = *(const float4*)&wsm[tx * 4 + j][kk];
                acc[0][j] += a0.x * b.x + a0.y * b.y + a0.z * b.z + a0.w * b.w;
                acc[1][j] += a1.x * b.x + a1.y * b.y + a1.z * b.z + a1.w * b.w;
            }
        }
        __syncthreads();
    }
    #pragma unroll
    for (int i = 0; i < 2; i++)
        #pragma unroll
        for (int j = 0; j < 4; j++)
            scores[(size_t)(t0 + ty * 2 + i) * E_NUM + tx * 4 + j] =
                1.f / (1.f + __expf(-acc[i][j]));
}

// ---------------- router part 2: wave-parallel grouped top-k ----------------
__global__ __launch_bounds__(256)
void topk_k(const float* __restrict__ scores, const float* __restrict__ ebias,
            int* __restrict__ topk_idx, float* __restrict__ topk_w,
            int* __restrict__ counts) {
    int t = blockIdx.x * 4 + (threadIdx.x >> 6);
    int e = threadIdx.x & 63;
    float sc = scores[(size_t)t * E_NUM + e];
    float sb = sc + ebias[e];
    float m1 = sb, m2 = -1e30f;
    #pragma unroll
    for (int off = 1; off <= 4; off <<= 1) {
        float o1 = __shfl_xor(m1, off);
        float o2 = __shfl_xor(m2, off);
        float hi = fmaxf(m1, o1), lo = fminf(m1, o1);
        m2 = fmaxf(lo, fmaxf(m2, o2));
        m1 = hi;
    }
    float grp = m1 + m2;
    float grpv[8];
    #pragma unroll
    for (int g = 0; g < 8; g++) grpv[g] = __shfl(grp, g * 8);
    unsigned gsel = 0;
    #pragma unroll
    for (int k = 0; k < 4; k++) {
        float best = -1e30f; int bi = 0;
        #pragma unroll
        for (int g = 0; g < 8; g++)
            if (!((gsel >> g) & 1) && grpv[g] > best) { best = grpv[g]; bi = g; }
        gsel |= 1u << bi;
    }
    float val = ((gsel >> (e >> 3)) & 1) ? sb : -1e30f;
    int idx[8]; float sv[8]; float wsum = 0.f;
    #pragma unroll
    for (int k = 0; k < 8; k++) {
        uint32_t u = __float_as_uint(val);
        uint32_t mu = (u & 0x80000000u) ? ~u : (u | 0x80000000u);
        unsigned long long key = ((unsigned long long)mu << 6) | (unsigned long long)(63 - e);
        #pragma unroll
        for (int off = 32; off; off >>= 1) {
            unsigned long long ok = __shfl_xor(key, off);
            if (ok > key) key = ok;
        }
        int win = 63 - (int)(key & 63ull);
        idx[k] = win;
        sv[k] = __shfl(sc, win);
        wsum += sv[k];
        if (e == win) val = -1e30f;
    }
    float inv = 1.f / (wsum + 1e-20f);
    if (e < 8) {
        topk_idx[t * 8 + e] = idx[e];
        topk_w[t * 8 + e] = sv[e] * inv;
        atomicAdd(&counts[idx[e]], 1);
    }
}

// exclusive scan over 64 expert counts + m-tile worklist build, one wave
__global__ void scan_k(const int* __restrict__ counts, int* __restrict__ base,
                       int* __restrict__ cursor, int* __restrict__ tile_e,
                       int* __restrict__ tile_m0) {
    int e = threadIdx.x;
    int c = counts[e];
    int s = c;
    #pragma unroll
    for (int off = 1; off < 64; off <<= 1) {
        int o = __shfl_up(s, off);
        if (e >= off) s += o;
    }
    int ex = s - c;
    base[e] = ex;
    cursor[e] = ex;
    int nt = (c + 127) >> 7;
    int ts = nt;
    #pragma unroll
    for (int off = 1; off < 64; off <<= 1) {
        int o = __shfl_up(ts, off);
        if (e >= off) ts += o;
    }
    int tb = ts - nt;
    for (int i = 0; i < nt; i++) { tile_e[tb + i] = e; tile_m0[tb + i] = i * 128; }
    int total = __shfl(ts, 63);
    for (int j = total + e; j < T_TILES; j += 64) tile_e[j] = -1;
}

__global__ void scatter_k(const int* __restrict__ topk_idx, const float* __restrict__ topk_w,
                          int* __restrict__ cursor, int* __restrict__ row_token,
                          float* __restrict__ row_wgt, int* __restrict__ pos_of) {
    int i = blockIdx.x * blockDim.x + threadIdx.x;
    int e = topk_idx[i];
    int pos = atomicAdd(&cursor[e], 1);
    row_token[pos] = i >> 3;
    row_wgt[pos] = topk_w[i];
    pos_of[i] = pos;
}

// ---------------- combine: out[t] += sum_k O[pos_of[t*8+k]] (weights pre-applied) ---
__global__ __launch_bounds__(256)
void combine_k(const float* __restrict__ O, const int* __restrict__ pos_of,
               float* __restrict__ out) {
    int t = blockIdx.x;
    int c = threadIdx.x;
    float4 s = ((const float4*)(out + (size_t)t * C_DIM))[c];
    int p[8];
    #pragma unroll
    for (int k = 0; k < 8; k++) p[k] = pos_of[t * 8 + k];
    #pragma unroll
    for (int k = 0; k < 8; k++) {
        float4 v = ((const float4*)(O + (size_t)p[k] * C_DIM))[c];
        s.x += v.x; s.y += v.y; s.z += v.z; s.w += v.w;
    }
    ((float4*)(out + (size_t)t * C_DIM))[c] = s;
}

// ---------------- prepass: fp32 -> bf16 elementwise (x) ----------------
__global__ void cvt_bf16_k(const float* __restrict__ in, unsigned short* __restrict__ out, int n8) {
    int i = blockIdx.x * blockDim.x + threadIdx.x;
    if (i >= n8) return;
    float4 v0 = ((const float4*)in)[2 * i];
    float4 v1 = ((const float4*)in)[2 * i + 1];
    unsigned short t[8] = { f2bf(v0.x), f2bf(v0.y), f2bf(v0.z), f2bf(v0.w),
                            f2bf(v1.x), f2bf(v1.y), f2bf(v1.z), f2bf(v1.w) };
    ((uint4*)out)[i] = *(uint4*)t;
}

// ---------------- GEMM: C[M,N] = A[M,K](bf16) @ B[K,N](fp32 native), fp32 acc ----
// A: global_load_lds into [128][32] bf16 LDS (linear). B: per-thread 16 coalesced
// dword loads (8 k's per column), f2bf in reg, short8 store into [BN][32] LDS
// with XOR swizzle (col8 ^ ((row&3)<<3)) on write AND read. 2-buffer, 1 barrier
// per K-step; B latency hides under MFMA (reg-held), A gl2lds under full phase.
// FUSED: BN=64 (B1,B2), else BN=128. EPI: 0 SwiGLU->bf16; 1 f32; 2 f32*w
template<bool FUSED, bool GATHER, bool WL, int EPI>
__global__ __launch_bounds__(256, 3)
void gemm2_k(const short* __restrict__ A, const float* __restrict__ B1f,
             const float* __restrict__ B2f, void* __restrict__ Cout,
             int M, int N, int K,
             const int* __restrict__ counts, const int* __restrict__ base,
             const int* __restrict__ row_token, const float* __restrict__ row_wgt,
             const int* __restrict__ tile_e, const int* __restrict__ tile_m0) {
    constexpr int BN = FUSED ? 64 : 128;
    constexpr int NJ = FUSED ? 2 : 4;
    constexpr int BS = BN * 32;            // B LDS shorts per buffer

    int e = 0, m0, Mrows, rowbase = 0;
    if (WL) {
        e = tile_e[blockIdx.y];
        if (e < 0) return;
        m0 = tile_m0[blockIdx.y];
        Mrows = counts[e];
        rowbase = base[e];
    } else {
        m0 = blockIdx.y * 128;
        Mrows = M;
    }
    int n0 = blockIdx.x * BN;
    const float* B1 = B1f + (WL ? (size_t)e * N * K : 0);
    const float* B2 = FUSED ? (B2f + (WL ? (size_t)e * N * K : 0)) : nullptr;

    __shared__ short As[2 * 4096];
    __shared__ short Bs1[2 * BS];
    __shared__ short Bs2[FUSED ? 2 * BS : 16];

    int tid = threadIdx.x;
    int lane = tid & 63, w = tid >> 6;
    int wr = w >> 1, wc = w & 1;
    int quad = lane >> 4, l16 = lane & 15;
    int sr = lane >> 2, sc = lane & 3;

    // A staging pointers (gl2lds; wave w covers rows w*32..w*32+31)
    const short* aptr[2];
    #pragma unroll
    for (int i = 0; i < 2; i++) {
        int row = w * 32 + i * 16 + sr;
        int mrow = m0 + row;
        int cl = mrow < Mrows ? mrow : (Mrows - 1);
        size_t arow;
        if (GATHER)  arow = (size_t)row_token[rowbase + cl];
        else if (WL) arow = (size_t)(rowbase + cl);
        else         arow = (size_t)mrow;
        aptr[i] = A + arow * K + sc * 8;
    }

    // B staging: thread -> column nb, k-rows kg*8..kg*8+7 (wave w = k-slice w)
    int nb = tid & 63, kg = tid >> 6;
    const float* b1g = B1 + (size_t)(kg * 8) * N + n0 + nb;
    const float* b2g = FUSED ? (B2 + (size_t)(kg * 8) * N + n0 + nb) : nullptr;
    const int bwr = nb * 32 + ((kg * 8) ^ ((nb & 3) << 3));   // swizzled short idx

    f32x4 acc1[4][NJ] = {};
    f32x4 acc2[FUSED ? 4 : 1][NJ] = {};

    const int nk = K >> 5;

    auto stageA = [&](int buf) {
        #pragma unroll
        for (int i = 0; i < 2; i++) {
            gl2lds16(aptr[i], &As[buf * 4096 + (w * 32 + i * 16) * 32]);
            aptr[i] += 32;
        }
    };
    auto loadB = [&](float (&fb)[2][8]) {
        #pragma unroll
        for (int jj = 0; jj < 8; jj++) fb[0][jj] = b1g[(size_t)jj * N];
        if constexpr (FUSED) {
            #pragma unroll
            for (int jj = 0; jj < 8; jj++) fb[1][jj] = b2g[(size_t)jj * N];
            b2g += (size_t)32 * N;
        } else {
            #pragma unroll
            for (int jj = 0; jj < 8; jj++) fb[1][jj] = b1g[(size_t)jj * N + 64];
        }
        b1g += (size_t)32 * N;
    };
    auto writeB = [&](int buf, float (&fb)[2][8]) {
        short8 v0, v1;
        #pragma unroll
        for (int jj = 0; jj < 8; jj++) {
            v0[jj] = (short)f2bf(fb[0][jj]);
            v1[jj] = (short)f2bf(fb[1][jj]);
        }
        *(short8*)&Bs1[buf * BS + bwr] = v0;
        if constexpr (FUSED) *(short8*)&Bs2[buf * BS + bwr] = v1;
        else                 *(short8*)&Bs1[buf * BS + bwr + 64 * 32] = v1;
    };

    // prologue: tile 0
    stageA(0);
    {
        float fb[2][8];
        loadB(fb);
        writeB(0, fb);
    }
    __syncthreads();

    for (int t = 0; t < nk; t++) {
        int buf = t & 1;
        bool more = (t + 1 < nk);
        float fb[2][8];
        if (more) { stageA(buf ^ 1); loadB(fb); }   // issue early: hides under MFMA

        short8 a[4], b1[NJ], b2[NJ];
        #pragma unroll
        for (int i = 0; i < 4; i++)
            a[i] = *(const short8*)&As[buf * 4096 + (wr * 64 + i * 16 + l16) * 32 + quad * 8];
        #pragma unroll
        for (int j = 0; j < NJ; j++) {
            int row = wc * (BN / 2) + j * 16 + l16;
            int ro = row * 32 + ((quad * 8) ^ ((row & 3) << 3));
            b1[j] = *(const short8*)&Bs1[buf * BS + ro];
            if constexpr (FUSED) b2[j] = *(const short8*)&Bs2[buf * BS + ro];
        }
        #pragma unroll
        for (int i = 0; i < 4; i++)
            #pragma unroll
            for (int j = 0; j < NJ; j++) {
                acc1[i][j] = __builtin_amdgcn_mfma_f32_16x16x32_bf16(a[i], b1[j], acc1[i][j], 0, 0, 0);
                if (FUSED)
                    acc2[i][j] = __builtin_amdgcn_mfma_f32_16x16x32_bf16(a[i], b2[j], acc2[i][j], 0, 0, 0);
            }
        if (more) writeB(buf ^ 1, fb);   // waits B loads here (post-MFMA)
        __syncthreads();                 // drains A gl2lds(t+1) + B ds_writes
    }

    constexpr int CB = BN / 2;
    #pragma unroll
    for (int i = 0; i < 4; i++) {
        #pragma unroll
        for (int rr = 0; rr < 4; rr++) {
            int row = m0 + wr * 64 + i * 16 + quad * 4 + rr;
            if (row >= Mrows) continue;
            size_t orow = WL ? (size_t)(rowbase + row) : (size_t)row;
            float scl = 0.f;
            if (EPI == 2) scl = row_wgt[rowbase + row];
            #pragma unroll
            for (int j = 0; j < NJ; j++) {
                int n = n0 + wc * CB + j * 16 + l16;
                float v = acc1[i][j][rr];
                if (EPI == 0) {
                    float u = acc2[i][j][rr];
                    float h = v / (1.f + __expf(-v)) * u;
                    ((unsigned short*)Cout)[orow * N + n] = f2bf(h);
                } else if (EPI == 1) {
                    ((float*)Cout)[orow * N + n] = v;
                } else {
                    ((float*)Cout)[orow * N + n] = v * scl;
                }
            }
        }
    }
}

// ---------------- launch ----------------
extern "C" void kernel_launch(void* const* d_in, const int* in_sizes, int n_in,
                              void* d_out, int out_size, void* d_ws, size_t ws_size,
                              hipStream_t stream) {
    const float* x        = (const float*)d_in[0];
    const float* router_w = (const float*)d_in[1];
    const float* e_bias   = (const float*)d_in[2];
    const float* gate_w   = (const float*)d_in[3];
    const float* up_w     = (const float*)d_in[4];
    const float* down_w   = (const float*)d_in[5];
    const float* sh_gate  = (const float*)d_in[6];
    const float* sh_up    = (const float*)d_in[7];
    const float* sh_down  = (const float*)d_in[8];
    float* out = (float*)d_out;
    char* ws = (char*)d_ws;

    int*   counts    = (int*)(ws);
    int*   base      = (int*)(ws + 256);
    int*   cursor    = (int*)(ws + 512);
    int*   topk_idx  = (int*)(ws + 1024);
    float* topk_w    = (float*)(ws + 1024 + 131072);
    int*   row_token = (int*)(ws + 1024 + 2 * 131072);
    float* row_wgt   = (float*)(ws + 1024 + 3 * 131072);
    float* scoresbuf = (float*)(ws + 1024 + 4 * 131072);           // 1 MB
    int*   pos_of    = (int*)(ws + 1664 * 1024);                   // 128 KB
    int*   tile_e    = (int*)(ws + 1800 * 1024);                   // 1.25 KB
    int*   tile_m0   = (int*)(ws + 1808 * 1024);                   // 1.25 KB
    const size_t MB = 1u << 20;
    unsigned short* xb = (unsigned short*)(ws + 2 * MB);           // 8 MB
    unsigned short* Hs = (unsigned short*)(ws + 10 * MB);          // 16 MB
    unsigned short* Hr = (unsigned short*)(ws + 26 * MB);          // 32 MB
    float*          O  = (float*)(ws + 70 * MB);                   // 128 MB

    // ---- routing ----
    router_scores_k<<<S_TOK / 32, 256, 0, stream>>>(x, router_w, scoresbuf, counts);
    topk_k<<<S_TOK / 4, 256, 0, stream>>>(scoresbuf, e_bias, topk_idx, topk_w, counts);
    scan_k<<<1, 64, 0, stream>>>(counts, base, cursor, tile_e, tile_m0);
    scatter_k<<<ROWS_TOTAL / 256, 256, 0, stream>>>(topk_idx, topk_w, cursor, row_token, row_wgt, pos_of);

    // ---- prepass: bf16 conversion of x only (weights consumed fp32-native) ----
    cvt_bf16_k<<<S_TOK * C_DIM / 8 / 256, 256, 0, stream>>>(x, xb, S_TOK * C_DIM / 8);

    // ---- shared expert ----
    gemm2_k<true, false, false, 0><<<dim3(HS_DIM / 64, S_TOK / 128, 1), 256, 0, stream>>>(
        (const short*)xb, sh_gate, sh_up, Hs,
        S_TOK, HS_DIM, C_DIM, nullptr, nullptr, nullptr, nullptr, nullptr, nullptr);
    gemm2_k<false, false, false, 1><<<dim3(C_DIM / 128, S_TOK / 128, 1), 256, 0, stream>>>(
        (const short*)Hs, sh_down, nullptr, out,
        S_TOK, C_DIM, HS_DIM, nullptr, nullptr, nullptr, nullptr, nullptr, nullptr);

    // ---- routed experts (worklist-balanced) ----
    gemm2_k<true, true, true, 0><<<dim3(H_DIM / 64, T_TILES, 1), 256, 0, stream>>>(
        (const short*)xb, gate_w, up_w, Hr,
        0, H_DIM, C_DIM, counts, base, row_token, row_wgt, tile_e, tile_m0);
    gemm2_k<false, false, true, 2><<<dim3(C_DIM / 128, T_TILES, 1), 256, 0, stream>>>(
        (const short*)Hr, down_w, nullptr, O,
        0, C_DIM, H_DIM, counts, base, row_token, row_wgt, tile_e, tile_m0);

    // ---- combine routed into out (out already holds shared-expert result) ----
    combine_k<<<S_TOK, 256, 0, stream>>>(O, pos_of, out);
}

// Round 6
// 868.507 us; speedup vs baseline: 1.1743x; 1.0148x over previous
//
#include <hip/hip_runtime.h>
#include <hip/hip_bf16.h>
#include <stdint.h>

// MoE FFN: sigmoid router (group-limited greedy top-8 of 64), SwiGLU experts
// (1024->512->1024) + shared expert (1024->2048->1024). All inputs fp32.
// R9: fp32-native weights kept (no transpose prepass, R8), but the two R8
// regressions fixed: (a) B fp32->bf16 convert now v_cvt_pk_bf16_f32 (1 instr
// per 2 elems, HW RNE; was ~4 VALU x16 = VALU-bound), (b) deep pipeline
// restored: A = 3-slot gl2lds ring staged 2 ahead; B = 2-deep register
// prefetch (ping-pong fbA/fbB, static names) written to 2-buffer LDS 1 ahead;
// one raw s_barrier per K-step with counted s_waitcnt vmcnt(18) (A(t+2)x2 +
// B(t+2)x16 in flight) instead of __syncthreads' vmcnt(0) drain.
// Worklist balancing (R6) + combine-not-atomics (R5) kept.

#define S_TOK 4096
#define C_DIM 1024
#define E_NUM 64
#define H_DIM 512
#define HS_DIM 2048
#define ROWS_TOTAL (S_TOK * 8)
#define T_TILES 320   // ROWS_TOTAL/128 + E_NUM upper bound on routed m-tiles

typedef __attribute__((ext_vector_type(8))) short short8;
typedef __attribute__((ext_vector_type(4))) float f32x4;

static __device__ __forceinline__ unsigned short f2bf(float f) {
    union { float f; uint32_t u; } v; v.f = f;
    uint32_t u = v.u;
    u += 0x7fffu + ((u >> 16) & 1u);   // RNE
    return (unsigned short)(u >> 16);
}

static __device__ __forceinline__ void gl2lds16(const void* g, void* l) {
    __builtin_amdgcn_global_load_lds(
        (const __attribute__((address_space(1))) uint32_t*)g,
        (__attribute__((address_space(3))) uint32_t*)l, 16, 0, 0);
}

// ---------------- router part 1: scores = sigmoid(x @ rw^T), fp32 ----------------
__global__ __launch_bounds__(256)
void router_scores_k(const float* __restrict__ x, const float* __restrict__ rw,
                     float* __restrict__ scores, int* __restrict__ counts) {
    if (blockIdx.x == 0 && threadIdx.x < E_NUM) counts[threadIdx.x] = 0;
    int t0 = blockIdx.x * 32;
    __shared__ float xs[32][36];
    __shared__ float wsm[64][36];
    int t = threadIdx.x;
    int tx = t & 15, ty = t >> 4;
    float acc[2][4] = {};
    for (int k0 = 0; k0 < C_DIM; k0 += 32) {
        {
            int r = t >> 3, c = t & 7;
            *(float4*)&xs[r][c * 4] = *(const float4*)(x + (size_t)(t0 + r) * C_DIM + k0 + c * 4);
        }
        #pragma unroll
        for (int i = 0; i < 2; i++) {
            int idx = t + 256 * i;
            int r = idx >> 3, c = idx & 7;
            *(float4*)&wsm[r][c * 4] = *(const float4*)(rw + (size_t)r * C_DIM + k0 + c * 4);
        }
        __syncthreads();
        #pragma unroll
        for (int kk = 0; kk < 32; kk += 4) {
            float4 a0 = *(const float4*)&xs[ty * 2 + 0][kk];
            float4 a1 = *(const float4*)&xs[ty * 2 + 1][kk];
            #pragma unroll
            for (int j = 0; j < 4; j++) {
                float4 b = *(const float4*)&wsm[tx * 4 + j][kk];
                acc[0][j] += a0.x * b.x + a0.y * b.y + a0.z * b.z + a0.w * b.w;
                acc[1][j] += a1.x * b.x + a1.y * b.y + a1.z * b.z + a1.w * b.w;
            }
        }
        __syncthreads();
    }
    #pragma unroll
    for (int i = 0; i < 2; i++)
        #pragma unroll
        for (int j = 0; j < 4; j++)
            scores[(size_t)(t0 + ty * 2 + i) * E_NUM + tx * 4 + j] =
                1.f / (1.f + __expf(-acc[i][j]));
}

// ---------------- router part 2: wave-parallel grouped top-k ----------------
__global__ __launch_bounds__(256)
void topk_k(const float* __restrict__ scores, const float* __restrict__ ebias,
            int* __restrict__ topk_idx, float* __restrict__ topk_w,
            int* __restrict__ counts) {
    int t = blockIdx.x * 4 + (threadIdx.x >> 6);
    int e = threadIdx.x & 63;
    float sc = scores[(size_t)t * E_NUM + e];
    float sb = sc + ebias[e];
    float m1 = sb, m2 = -1e30f;
    #pragma unroll
    for (int off = 1; off <= 4; off <<= 1) {
        float o1 = __shfl_xor(m1, off);
        float o2 = __shfl_xor(m2, off);
        float hi = fmaxf(m1, o1), lo = fminf(m1, o1);
        m2 = fmaxf(lo, fmaxf(m2, o2));
        m1 = hi;
    }
    float grp = m1 + m2;
    float grpv[8];
    #pragma unroll
    for (int g = 0; g < 8; g++) grpv[g] = __shfl(grp, g * 8);
    unsigned gsel = 0;
    #pragma unroll
    for (int k = 0; k < 4; k++) {
        float best = -1e30f; int bi = 0;
        #pragma unroll
        for (int g = 0; g < 8; g++)
            if (!((gsel >> g) & 1) && grpv[g] > best) { best = grpv[g]; bi = g; }
        gsel |= 1u << bi;
    }
    float val = ((gsel >> (e >> 3)) & 1) ? sb : -1e30f;
    int idx[8]; float sv[8]; float wsum = 0.f;
    #pragma unroll
    for (int k = 0; k < 8; k++) {
        uint32_t u = __float_as_uint(val);
        uint32_t mu = (u & 0x80000000u) ? ~u : (u | 0x80000000u);
        unsigned long long key = ((unsigned long long)mu << 6) | (unsigned long long)(63 - e);
        #pragma unroll
        for (int off = 32; off; off >>= 1) {
            unsigned long long ok = __shfl_xor(key, off);
            if (ok > key) key = ok;
        }
        int win = 63 - (int)(key & 63ull);
        idx[k] = win;
        sv[k] = __shfl(sc, win);
        wsum += sv[k];
        if (e == win) val = -1e30f;
    }
    float inv = 1.f / (wsum + 1e-20f);
    if (e < 8) {
        topk_idx[t * 8 + e] = idx[e];
        topk_w[t * 8 + e] = sv[e] * inv;
        atomicAdd(&counts[idx[e]], 1);
    }
}

// exclusive scan over 64 expert counts + m-tile worklist build, one wave
__global__ void scan_k(const int* __restrict__ counts, int* __restrict__ base,
                       int* __restrict__ cursor, int* __restrict__ tile_e,
                       int* __restrict__ tile_m0) {
    int e = threadIdx.x;
    int c = counts[e];
    int s = c;
    #pragma unroll
    for (int off = 1; off < 64; off <<= 1) {
        int o = __shfl_up(s, off);
        if (e >= off) s += o;
    }
    int ex = s - c;
    base[e] = ex;
    cursor[e] = ex;
    int nt = (c + 127) >> 7;
    int ts = nt;
    #pragma unroll
    for (int off = 1; off < 64; off <<= 1) {
        int o = __shfl_up(ts, off);
        if (e >= off) ts += o;
    }
    int tb = ts - nt;
    for (int i = 0; i < nt; i++) { tile_e[tb + i] = e; tile_m0[tb + i] = i * 128; }
    int total = __shfl(ts, 63);
    for (int j = total + e; j < T_TILES; j += 64) tile_e[j] = -1;
}

__global__ void scatter_k(const int* __restrict__ topk_idx, const float* __restrict__ topk_w,
                          int* __restrict__ cursor, int* __restrict__ row_token,
                          float* __restrict__ row_wgt, int* __restrict__ pos_of) {
    int i = blockIdx.x * blockDim.x + threadIdx.x;
    int e = topk_idx[i];
    int pos = atomicAdd(&cursor[e], 1);
    row_token[pos] = i >> 3;
    row_wgt[pos] = topk_w[i];
    pos_of[i] = pos;
}

// ---------------- combine: out[t] += sum_k O[pos_of[t*8+k]] (weights pre-applied) ---
__global__ __launch_bounds__(256)
void combine_k(const float* __restrict__ O, const int* __restrict__ pos_of,
               float* __restrict__ out) {
    int t = blockIdx.x;
    int c = threadIdx.x;
    float4 s = ((const float4*)(out + (size_t)t * C_DIM))[c];
    int p[8];
    #pragma unroll
    for (int k = 0; k < 8; k++) p[k] = pos_of[t * 8 + k];
    #pragma unroll
    for (int k = 0; k < 8; k++) {
        float4 v = ((const float4*)(O + (size_t)p[k] * C_DIM))[c];
        s.x += v.x; s.y += v.y; s.z += v.z; s.w += v.w;
    }
    ((float4*)(out + (size_t)t * C_DIM))[c] = s;
}

// ---------------- prepass: fp32 -> bf16 elementwise (x) ----------------
__global__ void cvt_bf16_k(const float* __restrict__ in, unsigned short* __restrict__ out, int n8) {
    int i = blockIdx.x * blockDim.x + threadIdx.x;
    if (i >= n8) return;
    float4 v0 = ((const float4*)in)[2 * i];
    float4 v1 = ((const float4*)in)[2 * i + 1];
    unsigned short t[8] = { f2bf(v0.x), f2bf(v0.y), f2bf(v0.z), f2bf(v0.w),
                            f2bf(v1.x), f2bf(v1.y), f2bf(v1.z), f2bf(v1.w) };
    ((uint4*)out)[i] = *(uint4*)t;
}

// ---------------- GEMM: C[M,N] = A[M,K](bf16) @ B[K,N](fp32 native), fp32 acc ----
// A: 3-slot gl2lds ring, staged 2 K-steps ahead. B: fp32 column-gather loads
// 2 K-steps ahead into ping-pong regs (fbA/fbB), v_cvt_pk_bf16_f32 convert,
// short8 LDS write 1 step ahead (2-buffer, XOR-swizzled write+read). One raw
// s_barrier per step, counted s_waitcnt vmcnt(18) (= A(t+2)x2 + B(t+2)x16).
// FUSED: BN=64 (B1,B2), else BN=128. EPI: 0 SwiGLU->bf16; 1 f32; 2 f32*w
template<bool FUSED, bool GATHER, bool WL, int EPI>
__global__ __launch_bounds__(256, 3)
void gemm2_k(const short* __restrict__ A, const float* __restrict__ B1f,
             const float* __restrict__ B2f, void* __restrict__ Cout,
             int M, int N, int K,
             const int* __restrict__ counts, const int* __restrict__ base,
             const int* __restrict__ row_token, const float* __restrict__ row_wgt,
             const int* __restrict__ tile_e, const int* __restrict__ tile_m0) {
    constexpr int BN = FUSED ? 64 : 128;
    constexpr int NJ = FUSED ? 2 : 4;
    constexpr int BS = BN * 32;            // B LDS shorts per buffer

    int e = 0, m0, Mrows, rowbase = 0;
    if (WL) {
        e = tile_e[blockIdx.y];
        if (e < 0) return;
        m0 = tile_m0[blockIdx.y];
        Mrows = counts[e];
        rowbase = base[e];
    } else {
        m0 = blockIdx.y * 128;
        Mrows = M;
    }
    int n0 = blockIdx.x * BN;
    const float* B1 = B1f + (WL ? (size_t)e * N * K : 0);
    const float* B2 = FUSED ? (B2f + (WL ? (size_t)e * N * K : 0)) : nullptr;

    __shared__ short As[3 * 4096];                 // 3 x 128x32 (24 KB)
    __shared__ short Bs1[2 * BS];
    __shared__ short Bs2[FUSED ? 2 * BS : 16];

    int tid = threadIdx.x;
    int lane = tid & 63, w = tid >> 6;
    int wr = w >> 1, wc = w & 1;
    int quad = lane >> 4, l16 = lane & 15;
    int sr = lane >> 2, sc = lane & 3;

    // A staging pointers (gl2lds; wave w covers rows w*32..w*32+31)
    const short* aptr[2];
    #pragma unroll
    for (int i = 0; i < 2; i++) {
        int row = w * 32 + i * 16 + sr;
        int mrow = m0 + row;
        int cl = mrow < Mrows ? mrow : (Mrows - 1);
        size_t arow;
        if (GATHER)  arow = (size_t)row_token[rowbase + cl];
        else if (WL) arow = (size_t)(rowbase + cl);
        else         arow = (size_t)mrow;
        aptr[i] = A + arow * K + sc * 8;
    }

    // B staging: thread -> column nb, k-rows kg*8..kg*8+7 (wave w = k-slice w)
    int nb = tid & 63, kg = tid >> 6;
    const float* b1g = B1 + (size_t)(kg * 8) * N + n0 + nb;
    const float* b2g = FUSED ? (B2 + (size_t)(kg * 8) * N + n0 + nb) : nullptr;
    const int bwr = nb * 32 + ((kg * 8) ^ ((nb & 3) << 3));   // swizzled short idx

    f32x4 acc1[4][NJ] = {};
    f32x4 acc2[FUSED ? 4 : 1][NJ] = {};

    const int nk = K >> 5;

    auto stageA = [&](int slot) {
        #pragma unroll
        for (int i = 0; i < 2; i++) {
            gl2lds16(aptr[i], &As[slot * 4096 + (w * 32 + i * 16) * 32]);
            aptr[i] += 32;
        }
    };
    auto loadB = [&](float (&fb)[2][8]) {
        #pragma unroll
        for (int jj = 0; jj < 8; jj++) fb[0][jj] = b1g[(size_t)jj * N];
        if constexpr (FUSED) {
            #pragma unroll
            for (int jj = 0; jj < 8; jj++) fb[1][jj] = b2g[(size_t)jj * N];
            b2g += (size_t)32 * N;
        } else {
            #pragma unroll
            for (int jj = 0; jj < 8; jj++) fb[1][jj] = b1g[(size_t)jj * N + 64];
        }
        b1g += (size_t)32 * N;
    };
    auto cvtpk = [](float a, float b) -> uint32_t {
        uint32_t r;
        asm("v_cvt_pk_bf16_f32 %0, %1, %2" : "=v"(r) : "v"(a), "v"(b));
        return r;
    };
    auto writeB = [&](int buf, float (&fb)[2][8]) {
        uint32_t w0[4], w1[4];
        #pragma unroll
        for (int q = 0; q < 4; q++) {
            w0[q] = cvtpk(fb[0][2 * q], fb[0][2 * q + 1]);
            w1[q] = cvtpk(fb[1][2 * q], fb[1][2 * q + 1]);
        }
        *(uint4*)&Bs1[buf * BS + bwr] = *(uint4*)w0;
        if constexpr (FUSED) *(uint4*)&Bs2[buf * BS + bwr] = *(uint4*)w1;
        else                 *(uint4*)&Bs1[buf * BS + bwr + 64 * 32] = *(uint4*)w1;
    };

    float fbA[2][8], fbB[2][8];
    // prologue: A tiles 0,1 -> slots 0,1; B tile0 -> LDS buf0; B tile1 -> fbA
    stageA(0);
    if (nk > 1) stageA(1);
    __builtin_amdgcn_sched_barrier(0);     // pin issue order for counted waits
    {
        float fb0[2][8];
        loadB(fb0);
        writeB(0, fb0);                    // implicit vmcnt wait on fb0
    }
    __builtin_amdgcn_sched_barrier(0);
    if (nk > 1) loadB(fbA);
    asm volatile("s_waitcnt vmcnt(16) lgkmcnt(0)" ::: "memory");  // leave fbA in flight
    __builtin_amdgcn_s_barrier();
    __builtin_amdgcn_sched_barrier(0);

    auto kstep = [&](int t, float (&fbIn)[2][8], float (&fbOut)[2][8]) {
        int slot = t % 3;
        int bbuf = t & 1;
        bool pf = (t + 2 < nk);
        if (pf) { stageA((t + 2) % 3); loadB(fbOut); }   // 2-ahead issue

        short8 a[4], b1[NJ], b2[NJ];
        #pragma unroll
        for (int i = 0; i < 4; i++)
            a[i] = *(const short8*)&As[slot * 4096 + (wr * 64 + i * 16 + l16) * 32 + quad * 8];
        #pragma unroll
        for (int j = 0; j < NJ; j++) {
            int row = wc * (BN / 2) + j * 16 + l16;
            int ro = row * 32 + ((quad * 8) ^ ((row & 3) << 3));
            b1[j] = *(const short8*)&Bs1[bbuf * BS + ro];
            if constexpr (FUSED) b2[j] = *(const short8*)&Bs2[bbuf * BS + ro];
        }
        #pragma unroll
        for (int i = 0; i < 4; i++)
            #pragma unroll
            for (int j = 0; j < NJ; j++) {
                acc1[i][j] = __builtin_amdgcn_mfma_f32_16x16x32_bf16(a[i], b1[j], acc1[i][j], 0, 0, 0);
                if (FUSED)
                    acc2[i][j] = __builtin_amdgcn_mfma_f32_16x16x32_bf16(a[i], b2[j], acc2[i][j], 0, 0, 0);
            }
        if (t + 1 < nk) {
            writeB((t + 1) & 1, fbIn);     // tile t+1 -> other B buffer
            if (pf) asm volatile("s_waitcnt vmcnt(18) lgkmcnt(0)" ::: "memory");
            else    asm volatile("s_waitcnt vmcnt(0) lgkmcnt(0)" ::: "memory");
            __builtin_amdgcn_s_barrier();
            __builtin_amdgcn_sched_barrier(0);
        }
    };

    for (int t = 0; t < nk; t += 2) {
        kstep(t, fbA, fbB);
        if (t + 1 < nk) kstep(t + 1, fbB, fbA);
    }

    constexpr int CB = BN / 2;
    #pragma unroll
    for (int i = 0; i < 4; i++) {
        #pragma unroll
        for (int rr = 0; rr < 4; rr++) {
            int row = m0 + wr * 64 + i * 16 + quad * 4 + rr;
            if (row >= Mrows) continue;
            size_t orow = WL ? (size_t)(rowbase + row) : (size_t)row;
            float scl = 0.f;
            if (EPI == 2) scl = row_wgt[rowbase + row];
            #pragma unroll
            for (int j = 0; j < NJ; j++) {
                int n = n0 + wc * CB + j * 16 + l16;
                float v = acc1[i][j][rr];
                if (EPI == 0) {
                    float u = acc2[i][j][rr];
                    float h = v / (1.f + __expf(-v)) * u;
                    ((unsigned short*)Cout)[orow * N + n] = f2bf(h);
                } else if (EPI == 1) {
                    ((float*)Cout)[orow * N + n] = v;
                } else {
                    ((float*)Cout)[orow * N + n] = v * scl;
                }
            }
        }
    }
}

// ---------------- launch ----------------
extern "C" void kernel_launch(void* const* d_in, const int* in_sizes, int n_in,
                              void* d_out, int out_size, void* d_ws, size_t ws_size,
                              hipStream_t stream) {
    const float* x        = (const float*)d_in[0];
    const float* router_w = (const float*)d_in[1];
    const float* e_bias   = (const float*)d_in[2];
    const float* gate_w   = (const float*)d_in[3];
    const float* up_w     = (const float*)d_in[4];
    const float* down_w   = (const float*)d_in[5];
    const float* sh_gate  = (const float*)d_in[6];
    const float* sh_up    = (const float*)d_in[7];
    const float* sh_down  = (const float*)d_in[8];
    float* out = (float*)d_out;
    char* ws = (char*)d_ws;

    int*   counts    = (int*)(ws);
    int*   base      = (int*)(ws + 256);
    int*   cursor    = (int*)(ws + 512);
    int*   topk_idx  = (int*)(ws + 1024);
    float* topk_w    = (float*)(ws + 1024 + 131072);
    int*   row_token = (int*)(ws + 1024 + 2 * 131072);
    float* row_wgt   = (float*)(ws + 1024 + 3 * 131072);
    float* scoresbuf = (float*)(ws + 1024 + 4 * 131072);           // 1 MB
    int*   pos_of    = (int*)(ws + 1664 * 1024);                   // 128 KB
    int*   tile_e    = (int*)(ws + 1800 * 1024);                   // 1.25 KB
    int*   tile_m0   = (int*)(ws + 1808 * 1024);                   // 1.25 KB
    const size_t MB = 1u << 20;
    unsigned short* xb = (unsigned short*)(ws + 2 * MB);           // 8 MB
    unsigned short* Hs = (unsigned short*)(ws + 10 * MB);          // 16 MB
    unsigned short* Hr = (unsigned short*)(ws + 26 * MB);          // 32 MB
    float*          O  = (float*)(ws + 70 * MB);                   // 128 MB

    // ---- routing ----
    router_scores_k<<<S_TOK / 32, 256, 0, stream>>>(x, router_w, scoresbuf, counts);
    topk_k<<<S_TOK / 4, 256, 0, stream>>>(scoresbuf, e_bias, topk_idx, topk_w, counts);
    scan_k<<<1, 64, 0, stream>>>(counts, base, cursor, tile_e, tile_m0);
    scatter_k<<<ROWS_TOTAL / 256, 256, 0, stream>>>(topk_idx, topk_w, cursor, row_token, row_wgt, pos_of);

    // ---- prepass: bf16 conversion of x only (weights consumed fp32-native) ----
    cvt_bf16_k<<<S_TOK * C_DIM / 8 / 256, 256, 0, stream>>>(x, xb, S_TOK * C_DIM / 8);

    // ---- shared expert ----
    gemm2_k<true, false, false, 0><<<dim3(HS_DIM / 64, S_TOK / 128, 1), 256, 0, stream>>>(
        (const short*)xb, sh_gate, sh_up, Hs,
        S_TOK, HS_DIM, C_DIM, nullptr, nullptr, nullptr, nullptr, nullptr, nullptr);
    gemm2_k<false, false, false, 1><<<dim3(C_DIM / 128, S_TOK / 128, 1), 256, 0, stream>>>(
        (const short*)Hs, sh_down, nullptr, out,
        S_TOK, C_DIM, HS_DIM, nullptr, nullptr, nullptr, nullptr, nullptr, nullptr);

    // ---- routed experts (worklist-balanced) ----
    gemm2_k<true, true, true, 0><<<dim3(H_DIM / 64, T_TILES, 1), 256, 0, stream>>>(
        (const short*)xb, gate_w, up_w, Hr,
        0, H_DIM, C_DIM, counts, base, row_token, row_wgt, tile_e, tile_m0);
    gemm2_k<false, false, true, 2><<<dim3(C_DIM / 128, T_TILES, 1), 256, 0, stream>>>(
        (const short*)Hr, down_w, nullptr, O,
        0, C_DIM, H_DIM, counts, base, row_token, row_wgt, tile_e, tile_m0);

    // ---- combine routed into out (out already holds shared-expert result) ----
    combine_k<<<S_TOK, 256, 0, stream>>>(O, pos_of, out);
}

// Round 7
// 859.914 us; speedup vs baseline: 1.1860x; 1.0100x over previous
//
#include <hip/hip_runtime.h>
#include <hip/hip_bf16.h>
#include <stdint.h>

// MoE FFN: sigmoid router (group-limited greedy top-8 of 64), SwiGLU experts
// (1024->512->1024) + shared expert (1024->2048->1024). All inputs fp32.
// R10: latency-depth fix. R9 was latency-bound (all pipes <30%): pipeline
// depth 2 < ~900cy HBM latency / ~400cy step. Now: A = 4-slot gl2lds ring
// staged 3 K-steps ahead; B = 3-deep fp32 register rotation (fbA/fbB/fbC,
// static names) -> cvt_pk -> LDS 1 step ahead; counted s_waitcnt
// vmcnt(36/18/0) + raw s_barrier per step. Also: A-read 8-way bank conflict
// killed via both-sides XOR slot swizzle (pre-swizzled gl2lds GLOBAL source,
// m173 pattern; matching ^ on ds_read). B LDS was already swizzled.
// Worklist balancing (R6) + combine-not-atomics (R5) + fp32-native weights
// with cvt_pk (R8/R9) kept.

#define S_TOK 4096
#define C_DIM 1024
#define E_NUM 64
#define H_DIM 512
#define HS_DIM 2048
#define ROWS_TOTAL (S_TOK * 8)
#define T_TILES 320   // ROWS_TOTAL/128 + E_NUM upper bound on routed m-tiles

typedef __attribute__((ext_vector_type(8))) short short8;
typedef __attribute__((ext_vector_type(4))) float f32x4;

static __device__ __forceinline__ unsigned short f2bf(float f) {
    union { float f; uint32_t u; } v; v.f = f;
    uint32_t u = v.u;
    u += 0x7fffu + ((u >> 16) & 1u);   // RNE
    return (unsigned short)(u >> 16);
}

static __device__ __forceinline__ void gl2lds16(const void* g, void* l) {
    __builtin_amdgcn_global_load_lds(
        (const __attribute__((address_space(1))) uint32_t*)g,
        (__attribute__((address_space(3))) uint32_t*)l, 16, 0, 0);
}

// ---------------- router part 1: scores = sigmoid(x @ rw^T), fp32 ----------------
__global__ __launch_bounds__(256)
void router_scores_k(const float* __restrict__ x, const float* __restrict__ rw,
                     float* __restrict__ scores, int* __restrict__ counts) {
    if (blockIdx.x == 0 && threadIdx.x < E_NUM) counts[threadIdx.x] = 0;
    int t0 = blockIdx.x * 32;
    __shared__ float xs[32][36];
    __shared__ float wsm[64][36];
    int t = threadIdx.x;
    int tx = t & 15, ty = t >> 4;
    float acc[2][4] = {};
    for (int k0 = 0; k0 < C_DIM; k0 += 32) {
        {
            int r = t >> 3, c = t & 7;
            *(float4*)&xs[r][c * 4] = *(const float4*)(x + (size_t)(t0 + r) * C_DIM + k0 + c * 4);
        }
        #pragma unroll
        for (int i = 0; i < 2; i++) {
            int idx = t + 256 * i;
            int r = idx >> 3, c = idx & 7;
            *(float4*)&wsm[r][c * 4] = *(const float4*)(rw + (size_t)r * C_DIM + k0 + c * 4);
        }
        __syncthreads();
        #pragma unroll
        for (int kk = 0; kk < 32; kk += 4) {
            float4 a0 = *(const float4*)&xs[ty * 2 + 0][kk];
            float4 a1 = *(const float4*)&xs[ty * 2 + 1][kk];
            #pragma unroll
            for (int j = 0; j < 4; j++) {
                float4 b = *(const float4*)&wsm[tx * 4 + j][kk];
                acc[0][j] += a0.x * b.x + a0.y * b.y + a0.z * b.z + a0.w * b.w;
                acc[1][j] += a1.x * b.x + a1.y * b.y + a1.z * b.z + a1.w * b.w;
            }
        }
        __syncthreads();
    }
    #pragma unroll
    for (int i = 0; i < 2; i++)
        #pragma unroll
        for (int j = 0; j < 4; j++)
            scores[(size_t)(t0 + ty * 2 + i) * E_NUM + tx * 4 + j] =
                1.f / (1.f + __expf(-acc[i][j]));
}

// ---------------- router part 2: wave-parallel grouped top-k ----------------
__global__ __launch_bounds__(256)
void topk_k(const float* __restrict__ scores, const float* __restrict__ ebias,
            int* __restrict__ topk_idx, float* __restrict__ topk_w,
            int* __restrict__ counts) {
    int t = blockIdx.x * 4 + (threadIdx.x >> 6);
    int e = threadIdx.x & 63;
    float sc = scores[(size_t)t * E_NUM + e];
    float sb = sc + ebias[e];
    float m1 = sb, m2 = -1e30f;
    #pragma unroll
    for (int off = 1; off <= 4; off <<= 1) {
        float o1 = __shfl_xor(m1, off);
        float o2 = __shfl_xor(m2, off);
        float hi = fmaxf(m1, o1), lo = fminf(m1, o1);
        m2 = fmaxf(lo, fmaxf(m2, o2));
        m1 = hi;
    }
    float grp = m1 + m2;
    float grpv[8];
    #pragma unroll
    for (int g = 0; g < 8; g++) grpv[g] = __shfl(grp, g * 8);
    unsigned gsel = 0;
    #pragma unroll
    for (int k = 0; k < 4; k++) {
        float best = -1e30f; int bi = 0;
        #pragma unroll
        for (int g = 0; g < 8; g++)
            if (!((gsel >> g) & 1) && grpv[g] > best) { best = grpv[g]; bi = g; }
        gsel |= 1u << bi;
    }
    float val = ((gsel >> (e >> 3)) & 1) ? sb : -1e30f;
    int idx[8]; float sv[8]; float wsum = 0.f;
    #pragma unroll
    for (int k = 0; k < 8; k++) {
        uint32_t u = __float_as_uint(val);
        uint32_t mu = (u & 0x80000000u) ? ~u : (u | 0x80000000u);
        unsigned long long key = ((unsigned long long)mu << 6) | (unsigned long long)(63 - e);
        #pragma unroll
        for (int off = 32; off; off >>= 1) {
            unsigned long long ok = __shfl_xor(key, off);
            if (ok > key) key = ok;
        }
        int win = 63 - (int)(key & 63ull);
        idx[k] = win;
        sv[k] = __shfl(sc, win);
        wsum += sv[k];
        if (e == win) val = -1e30f;
    }
    float inv = 1.f / (wsum + 1e-20f);
    if (e < 8) {
        topk_idx[t * 8 + e] = idx[e];
        topk_w[t * 8 + e] = sv[e] * inv;
        atomicAdd(&counts[idx[e]], 1);
    }
}

// exclusive scan over 64 expert counts + m-tile worklist build, one wave
__global__ void scan_k(const int* __restrict__ counts, int* __restrict__ base,
                       int* __restrict__ cursor, int* __restrict__ tile_e,
                       int* __restrict__ tile_m0) {
    int e = threadIdx.x;
    int c = counts[e];
    int s = c;
    #pragma unroll
    for (int off = 1; off < 64; off <<= 1) {
        int o = __shfl_up(s, off);
        if (e >= off) s += o;
    }
    int ex = s - c;
    base[e] = ex;
    cursor[e] = ex;
    int nt = (c + 127) >> 7;
    int ts = nt;
    #pragma unroll
    for (int off = 1; off < 64; off <<= 1) {
        int o = __shfl_up(ts, off);
        if (e >= off) ts += o;
    }
    int tb = ts - nt;
    for (int i = 0; i < nt; i++) { tile_e[tb + i] = e; tile_m0[tb + i] = i * 128; }
    int total = __shfl(ts, 63);
    for (int j = total + e; j < T_TILES; j += 64) tile_e[j] = -1;
}

__global__ void scatter_k(const int* __restrict__ topk_idx, const float* __restrict__ topk_w,
                          int* __restrict__ cursor, int* __restrict__ row_token,
                          float* __restrict__ row_wgt, int* __restrict__ pos_of) {
    int i = blockIdx.x * blockDim.x + threadIdx.x;
    int e = topk_idx[i];
    int pos = atomicAdd(&cursor[e], 1);
    row_token[pos] = i >> 3;
    row_wgt[pos] = topk_w[i];
    pos_of[i] = pos;
}

// ---------------- combine: out[t] += sum_k O[pos_of[t*8+k]] (weights pre-applied) ---
__global__ __launch_bounds__(256)
void combine_k(const float* __restrict__ O, const int* __restrict__ pos_of,
               float* __restrict__ out) {
    int t = blockIdx.x;
    int c = threadIdx.x;
    float4 s = ((const float4*)(out + (size_t)t * C_DIM))[c];
    int p[8];
    #pragma unroll
    for (int k = 0; k < 8; k++) p[k] = pos_of[t * 8 + k];
    #pragma unroll
    for (int k = 0; k < 8; k++) {
        float4 v = ((const float4*)(O + (size_t)p[k] * C_DIM))[c];
        s.x += v.x; s.y += v.y; s.z += v.z; s.w += v.w;
    }
    ((float4*)(out + (size_t)t * C_DIM))[c] = s;
}

// ---------------- prepass: fp32 -> bf16 elementwise (x) ----------------
__global__ void cvt_bf16_k(const float* __restrict__ in, unsigned short* __restrict__ out, int n8) {
    int i = blockIdx.x * blockDim.x + threadIdx.x;
    if (i >= n8) return;
    float4 v0 = ((const float4*)in)[2 * i];
    float4 v1 = ((const float4*)in)[2 * i + 1];
    unsigned short t[8] = { f2bf(v0.x), f2bf(v0.y), f2bf(v0.z), f2bf(v0.w),
                            f2bf(v1.x), f2bf(v1.y), f2bf(v1.z), f2bf(v1.w) };
    ((uint4*)out)[i] = *(uint4*)t;
}

// ---------------- GEMM: C[M,N] = A[M,K](bf16) @ B[K,N](fp32 native), fp32 acc ----
// Depth-3 pipeline: A 4-slot gl2lds ring staged 3 ahead (slot-XOR-swizzled via
// pre-swizzled global source); B fp32 col-gather 3 ahead into fbA/fbB/fbC reg
// sets, cvt_pk, LDS write 1 ahead (2-buffer, XOR-swizzled). Counted
// s_waitcnt vmcnt(36/18/0) + raw s_barrier per K-step.
// FUSED: BN=64 (B1,B2), else BN=128. EPI: 0 SwiGLU->bf16; 1 f32; 2 f32*w
template<bool FUSED, bool GATHER, bool WL, int EPI>
__global__ __launch_bounds__(256, 3)
void gemm2_k(const short* __restrict__ A, const float* __restrict__ B1f,
             const float* __restrict__ B2f, void* __restrict__ Cout,
             int M, int N, int K,
             const int* __restrict__ counts, const int* __restrict__ base,
             const int* __restrict__ row_token, const float* __restrict__ row_wgt,
             const int* __restrict__ tile_e, const int* __restrict__ tile_m0) {
    constexpr int BN = FUSED ? 64 : 128;
    constexpr int NJ = FUSED ? 2 : 4;
    constexpr int BS = BN * 32;            // B LDS shorts per buffer

    int e = 0, m0, Mrows, rowbase = 0;
    if (WL) {
        e = tile_e[blockIdx.y];
        if (e < 0) return;
        m0 = tile_m0[blockIdx.y];
        Mrows = counts[e];
        rowbase = base[e];
    } else {
        m0 = blockIdx.y * 128;
        Mrows = M;
    }
    int n0 = blockIdx.x * BN;
    const float* B1 = B1f + (WL ? (size_t)e * N * K : 0);
    const float* B2 = FUSED ? (B2f + (WL ? (size_t)e * N * K : 0)) : nullptr;

    __shared__ short As[4 * 4096];                 // 4-slot ring, 32 KB
    __shared__ short Bs1[2 * BS];
    __shared__ short Bs2[FUSED ? 2 * BS : 16];

    int tid = threadIdx.x;
    int lane = tid & 63, w = tid >> 6;
    int wr = w >> 1, wc = w & 1;
    int quad = lane >> 4, l16 = lane & 15;
    int sr = lane >> 2, sc = lane & 3;

    // A staging pointers (gl2lds; wave w covers rows w*32..w*32+31).
    // k-slot pre-swizzled in GLOBAL source: slot = sc ^ (row&3); row&3 == sr&3.
    const short* aptr[2];
    #pragma unroll
    for (int i = 0; i < 2; i++) {
        int row = w * 32 + i * 16 + sr;
        int mrow = m0 + row;
        int cl = mrow < Mrows ? mrow : (Mrows - 1);
        size_t arow;
        if (GATHER)  arow = (size_t)row_token[rowbase + cl];
        else if (WL) arow = (size_t)(rowbase + cl);
        else         arow = (size_t)mrow;
        aptr[i] = A + arow * K + ((sc ^ (sr & 3)) * 8);
    }

    // B staging: thread -> column nb, k-rows kg*8..kg*8+7 (wave w = k-slice w)
    int nb = tid & 63, kg = tid >> 6;
    const float* b1g = B1 + (size_t)(kg * 8) * N + n0 + nb;
    const float* b2g = FUSED ? (B2 + (size_t)(kg * 8) * N + n0 + nb) : nullptr;
    const int bwr = nb * 32 + ((kg * 8) ^ ((nb & 3) << 3));   // swizzled short idx

    f32x4 acc1[4][NJ] = {};
    f32x4 acc2[FUSED ? 4 : 1][NJ] = {};

    const int nk = K >> 5;

    auto stageA = [&](int slot) {
        #pragma unroll
        for (int i = 0; i < 2; i++) {
            gl2lds16(aptr[i], &As[slot * 4096 + (w * 32 + i * 16) * 32]);
            aptr[i] += 32;
        }
    };
    auto loadB = [&](float (&fb)[2][8]) {
        #pragma unroll
        for (int jj = 0; jj < 8; jj++) fb[0][jj] = b1g[(size_t)jj * N];
        if constexpr (FUSED) {
            #pragma unroll
            for (int jj = 0; jj < 8; jj++) fb[1][jj] = b2g[(size_t)jj * N];
            b2g += (size_t)32 * N;
        } else {
            #pragma unroll
            for (int jj = 0; jj < 8; jj++) fb[1][jj] = b1g[(size_t)jj * N + 64];
        }
        b1g += (size_t)32 * N;
    };
    auto cvtpk = [](float a, float b) -> uint32_t {
        uint32_t r;
        asm("v_cvt_pk_bf16_f32 %0, %1, %2" : "=v"(r) : "v"(a), "v"(b));
        return r;
    };
    auto writeB = [&](int buf, float (&fb)[2][8]) {
        uint32_t w0[4], w1[4];
        #pragma unroll
        for (int q = 0; q < 4; q++) {
            w0[q] = cvtpk(fb[0][2 * q], fb[0][2 * q + 1]);
            w1[q] = cvtpk(fb[1][2 * q], fb[1][2 * q + 1]);
        }
        *(uint4*)&Bs1[buf * BS + bwr] = *(uint4*)w0;
        if constexpr (FUSED) *(uint4*)&Bs2[buf * BS + bwr] = *(uint4*)w1;
        else                 *(uint4*)&Bs1[buf * BS + bwr + 64 * 32] = *(uint4*)w1;
    };

    float fbA[2][8], fbB[2][8], fbC[2][8];
    // prologue: B tile0 loads FIRST (oldest -> writeB's implicit wait leaves A in flight)
    {
        float fb0[2][8];
        loadB(fb0);                         // tile 0
        stageA(0);
        if (nk > 1) stageA(1);
        if (nk > 2) stageA(2);
        __builtin_amdgcn_sched_barrier(0);
        writeB(0, fb0);                     // waits fb0 only (6 A-loads newer)
    }
    __builtin_amdgcn_sched_barrier(0);
    if (nk > 1) loadB(fbA);                 // tile 1
    if (nk > 2) loadB(fbB);                 // tile 2
    // outstanding newest 36 = fbB(16)+fbA(16)+A2(2)+A1(2); waits A0
    asm volatile("s_waitcnt vmcnt(36) lgkmcnt(0)" ::: "memory");
    __builtin_amdgcn_s_barrier();
    __builtin_amdgcn_sched_barrier(0);

    auto kstep = [&](int t, float (&fbIn)[2][8], float (&fbOut)[2][8]) {
        int slot = t & 3;
        int bbuf = t & 1;
        bool pf = (t + 3 < nk);
        if (pf) { stageA((t + 3) & 3); loadB(fbOut); }   // 3-ahead issue

        short8 a[4], b1[NJ], b2[NJ];
        #pragma unroll
        for (int i = 0; i < 4; i++)
            a[i] = *(const short8*)&As[slot * 4096 + (wr * 64 + i * 16 + l16) * 32
                                       + ((quad ^ (l16 & 3)) * 8)];
        #pragma unroll
        for (int j = 0; j < NJ; j++) {
            int row = wc * (BN / 2) + j * 16 + l16;
            int ro = row * 32 + ((quad * 8) ^ ((row & 3) << 3));
            b1[j] = *(const short8*)&Bs1[bbuf * BS + ro];
            if constexpr (FUSED) b2[j] = *(const short8*)&Bs2[bbuf * BS + ro];
        }
        #pragma unroll
        for (int i = 0; i < 4; i++)
            #pragma unroll
            for (int j = 0; j < NJ; j++) {
                acc1[i][j] = __builtin_amdgcn_mfma_f32_16x16x32_bf16(a[i], b1[j], acc1[i][j], 0, 0, 0);
                if (FUSED)
                    acc2[i][j] = __builtin_amdgcn_mfma_f32_16x16x32_bf16(a[i], b2[j], acc2[i][j], 0, 0, 0);
            }
        if (t + 1 < nk) {
            writeB((t + 1) & 1, fbIn);     // tile t+1 -> other B buffer
            if (pf)                asm volatile("s_waitcnt vmcnt(36) lgkmcnt(0)" ::: "memory");
            else if (t + 2 < nk)   asm volatile("s_waitcnt vmcnt(18) lgkmcnt(0)" ::: "memory");
            else                   asm volatile("s_waitcnt vmcnt(0) lgkmcnt(0)" ::: "memory");
            __builtin_amdgcn_s_barrier();
            __builtin_amdgcn_sched_barrier(0);
        }
    };

    for (int t = 0; t < nk; t += 3) {
        kstep(t, fbA, fbC);
        if (t + 1 < nk) kstep(t + 1, fbB, fbA);
        if (t + 2 < nk) kstep(t + 2, fbC, fbB);
    }

    constexpr int CB = BN / 2;
    #pragma unroll
    for (int i = 0; i < 4; i++) {
        #pragma unroll
        for (int rr = 0; rr < 4; rr++) {
            int row = m0 + wr * 64 + i * 16 + quad * 4 + rr;
            if (row >= Mrows) continue;
            size_t orow = WL ? (size_t)(rowbase + row) : (size_t)row;
            float scl = 0.f;
            if (EPI == 2) scl = row_wgt[rowbase + row];
            #pragma unroll
            for (int j = 0; j < NJ; j++) {
                int n = n0 + wc * CB + j * 16 + l16;
                float v = acc1[i][j][rr];
                if (EPI == 0) {
                    float u = acc2[i][j][rr];
                    float h = v / (1.f + __expf(-v)) * u;
                    ((unsigned short*)Cout)[orow * N + n] = f2bf(h);
                } else if (EPI == 1) {
                    ((float*)Cout)[orow * N + n] = v;
                } else {
                    ((float*)Cout)[orow * N + n] = v * scl;
                }
            }
        }
    }
}

// ---------------- launch ----------------
extern "C" void kernel_launch(void* const* d_in, const int* in_sizes, int n_in,
                              void* d_out, int out_size, void* d_ws, size_t ws_size,
                              hipStream_t stream) {
    const float* x        = (const float*)d_in[0];
    const float* router_w = (const float*)d_in[1];
    const float* e_bias   = (const float*)d_in[2];
    const float* gate_w   = (const float*)d_in[3];
    const float* up_w     = (const float*)d_in[4];
    const float* down_w   = (const float*)d_in[5];
    const float* sh_gate  = (const float*)d_in[6];
    const float* sh_up    = (const float*)d_in[7];
    const float* sh_down  = (const float*)d_in[8];
    float* out = (float*)d_out;
    char* ws = (char*)d_ws;

    int*   counts    = (int*)(ws);
    int*   base      = (int*)(ws + 256);
    int*   cursor    = (int*)(ws + 512);
    int*   topk_idx  = (int*)(ws + 1024);
    float* topk_w    = (float*)(ws + 1024 + 131072);
    int*   row_token = (int*)(ws + 1024 + 2 * 131072);
    float* row_wgt   = (float*)(ws + 1024 + 3 * 131072);
    float* scoresbuf = (float*)(ws + 1024 + 4 * 131072);           // 1 MB
    int*   pos_of    = (int*)(ws + 1664 * 1024);                   // 128 KB
    int*   tile_e    = (int*)(ws + 1800 * 1024);                   // 1.25 KB
    int*   tile_m0   = (int*)(ws + 1808 * 1024);                   // 1.25 KB
    const size_t MB = 1u << 20;
    unsigned short* xb = (unsigned short*)(ws + 2 * MB);           // 8 MB
    unsigned short* Hs = (unsigned short*)(ws + 10 * MB);          // 16 MB
    unsigned short* Hr = (unsigned short*)(ws + 26 * MB);          // 32 MB
    float*          O  = (float*)(ws + 70 * MB);                   // 128 MB

    // ---- routing ----
    router_scores_k<<<S_TOK / 32, 256, 0, stream>>>(x, router_w, scoresbuf, counts);
    topk_k<<<S_TOK / 4, 256, 0, stream>>>(scoresbuf, e_bias, topk_idx, topk_w, counts);
    scan_k<<<1, 64, 0, stream>>>(counts, base, cursor, tile_e, tile_m0);
    scatter_k<<<ROWS_TOTAL / 256, 256, 0, stream>>>(topk_idx, topk_w, cursor, row_token, row_wgt, pos_of);

    // ---- prepass: bf16 conversion of x only (weights consumed fp32-native) ----
    cvt_bf16_k<<<S_TOK * C_DIM / 8 / 256, 256, 0, stream>>>(x, xb, S_TOK * C_DIM / 8);

    // ---- shared expert ----
    gemm2_k<true, false, false, 0><<<dim3(HS_DIM / 64, S_TOK / 128, 1), 256, 0, stream>>>(
        (const short*)xb, sh_gate, sh_up, Hs,
        S_TOK, HS_DIM, C_DIM, nullptr, nullptr, nullptr, nullptr, nullptr, nullptr);
    gemm2_k<false, false, false, 1><<<dim3(C_DIM / 128, S_TOK / 128, 1), 256, 0, stream>>>(
        (const short*)Hs, sh_down, nullptr, out,
        S_TOK, C_DIM, HS_DIM, nullptr, nullptr, nullptr, nullptr, nullptr, nullptr);

    // ---- routed experts (worklist-balanced) ----
    gemm2_k<true, true, true, 0><<<dim3(H_DIM / 64, T_TILES, 1), 256, 0, stream>>>(
        (const short*)xb, gate_w, up_w, Hr,
        0, H_DIM, C_DIM, counts, base, row_token, row_wgt, tile_e, tile_m0);
    gemm2_k<false, false, true, 2><<<dim3(C_DIM / 128, T_TILES, 1), 256, 0, stream>>>(
        (const short*)Hr, down_w, nullptr, O,
        0, C_DIM, H_DIM, counts, base, row_token, row_wgt, tile_e, tile_m0);

    // ---- combine routed into out (out already holds shared-expert result) ----
    combine_k<<<S_TOK, 256, 0, stream>>>(O, pos_of, out);
}